// Round 1
// baseline (490.921 us; speedup 1.0000x reference)
//
#include <hip/hip_runtime.h>
#include <math.h>

#define BV 2
#define TV 16
#define NV 2000
#define FIN 16
#define EV 32000
#define ETV 34000
#define GV 32
#define DD 64
#define FFV 2048

// workspace layout (float offsets)
#define OFF_H     0L
#define OFF_ASRC  8192000L
#define OFF_ADST  8448000L
#define OFF_Y     8704000L
#define OFF_Z1    12800000L
#define OFF_SCAL  13056000L   // [0]=ew_mean, [1..4]=s_h
#define OFF_INTS  13056016L   // rowptr[2001], cnt[2000], csr_src[34000]
#define OFF_CSREW 13094032L   // csr_ew[34000]

// ---------------- K0: ew_mean + per-head edge-attention scalars ----------------
__global__ void prep_kernel(const float* __restrict__ ew, const float* __restrict__ W_edge,
                            const float* __restrict__ att_edge, float* __restrict__ scal) {
    __shared__ float red[256];
    int tid = threadIdx.x;
    float s = 0.f;
    for (int i = tid; i < EV; i += 256) s += ew[i];
    red[tid] = s; __syncthreads();
    for (int d = 128; d > 0; d >>= 1) { if (tid < d) red[tid] += red[tid + d]; __syncthreads(); }
    if (tid == 0) scal[0] = red[0] / (float)EV;
    __syncthreads();
    float p = (tid < 128) ? W_edge[tid] * att_edge[tid] : 0.f;
    red[tid] = p; __syncthreads();
    if (tid < 4) {
        float t = 0.f;
        for (int c = 0; c < 32; c++) t += red[tid * 32 + c];
        scal[1 + tid] = t;
    }
}

// ---------------- K1: in-degree histogram (incl. self loops) ----------------
__global__ void hist_kernel(const int* __restrict__ edge_index, int* __restrict__ deg) {
    int e = blockIdx.x * 256 + threadIdx.x;
    if (e >= ETV) return;
    int dst = (e < EV) ? edge_index[EV + e] : (e - EV);
    atomicAdd(&deg[dst], 1);
}

// ---------------- K2: exclusive scan -> rowptr, copy -> cnt ----------------
__global__ void scan_kernel(const int* __restrict__ deg, int* __restrict__ rowptr, int* __restrict__ cnt) {
    __shared__ int tot[256];
    int tid = threadIdx.x;
    int base = tid * 8;
    int local[8]; int s = 0;
    for (int i = 0; i < 8; i++) { int v = (base + i < NV) ? deg[base + i] : 0; local[i] = s; s += v; }
    tot[tid] = s; __syncthreads();
    for (int d = 1; d < 256; d <<= 1) {
        int v = (tid >= d) ? tot[tid - d] : 0;
        __syncthreads();
        tot[tid] += v;
        __syncthreads();
    }
    int ex = tot[tid] - s;
    for (int i = 0; i < 8; i++) {
        int idx = base + i;
        if (idx < NV) { int rp = ex + local[i]; rowptr[idx] = rp; cnt[idx] = rp; }
    }
    if (tid == 255) rowptr[NV] = tot[255];
}

// ---------------- K3: scatter edges into CSR ----------------
__global__ void scatter_kernel(const int* __restrict__ edge_index, const float* __restrict__ edge_weight,
                               const float* __restrict__ scal, int* __restrict__ cnt,
                               int* __restrict__ csr_src, float* __restrict__ csr_ew) {
    int e = blockIdx.x * 256 + threadIdx.x;
    if (e >= ETV) return;
    int src, dst; float w;
    if (e < EV) { src = edge_index[e]; dst = edge_index[EV + e]; w = edge_weight[e]; }
    else        { src = dst = e - EV; w = scal[0]; }
    int pos = atomicAdd(&cnt[dst], 1);
    csr_src[pos] = src; csr_ew[pos] = w;
}

// ---------------- K4: h = x@W_gat, a_src, a_dst (one wave per (g,n) row) ----------------
__global__ __launch_bounds__(256) void gat_h_kernel(const float* __restrict__ x, const float* __restrict__ W_gat,
                                                    const float* __restrict__ att_src, const float* __restrict__ att_dst,
                                                    float* __restrict__ h, float* __restrict__ a_src, float* __restrict__ a_dst) {
    __shared__ float wg[16 * 128];
    int tid = threadIdx.x;
    for (int i = tid; i < 2048; i += 256) wg[i] = W_gat[i];
    __syncthreads();
    int wave = tid >> 6, lane = tid & 63;
    int row = blockIdx.x * 4 + wave;           // row = g*N + n
    const float* xr = x + (long)row * 16;
    float xv[16];
#pragma unroll
    for (int f = 0; f < 16; f++) xv[f] = xr[f];
    float h0 = 0.f, h1 = 0.f;
#pragma unroll
    for (int f = 0; f < 16; f++) { h0 += xv[f] * wg[f * 128 + lane]; h1 += xv[f] * wg[f * 128 + lane + 64]; }
    h[(long)row * 128 + lane] = h0;
    h[(long)row * 128 + lane + 64] = h1;
    // per-head attention scalars via butterfly within 32-lane halves
    float p0 = h0 * att_src[lane], p1 = h1 * att_src[lane + 64];
    float q0 = h0 * att_dst[lane], q1 = h1 * att_dst[lane + 64];
#pragma unroll
    for (int d = 1; d < 32; d <<= 1) {
        p0 += __shfl_xor(p0, d); p1 += __shfl_xor(p1, d);
        q0 += __shfl_xor(q0, d); q1 += __shfl_xor(q1, d);
    }
    if (lane == 0)  { a_src[row * 4 + 0] = p0; a_src[row * 4 + 2] = p1; a_dst[row * 4 + 0] = q0; a_dst[row * 4 + 2] = q1; }
    if (lane == 32) { a_src[row * 4 + 1] = p0; a_src[row * 4 + 3] = p1; a_dst[row * 4 + 1] = q0; a_dst[row * 4 + 3] = q1; }
}

// ---------------- K5: segment softmax + aggregation + head mean + W_proj -> y ----------------
__global__ __launch_bounds__(256) void gat_agg_kernel(const float* __restrict__ h, const float* __restrict__ a_src,
                                                      const float* __restrict__ a_dst, const int* __restrict__ rowptr,
                                                      const int* __restrict__ csr_src, const float* __restrict__ csr_ew,
                                                      const float* __restrict__ scal, const float* __restrict__ gat_bias,
                                                      const float* __restrict__ W_proj, const float* __restrict__ b_proj,
                                                      float* __restrict__ y) {
    __shared__ float wp[2048];
    int tid = threadIdx.x;
    for (int i = tid; i < 2048; i += 256) wp[i] = W_proj[i];
    __syncthreads();
    int lane = tid & 63, wave = tid >> 6;
    int w = blockIdx.x * 4 + wave;             // w = g*N + n
    int g = w / NV, n = w - g * NV;
    float s0 = scal[1], s1 = scal[2], s2 = scal[3], s3 = scal[4];
    const float4 ad = *(const float4*)(a_dst + (long)w * 4);
    const float* asrc_g = a_src + (long)g * NV * 4;
    const float* hg = h + (long)g * NV * 128;
    int start = rowptr[n], end = rowptr[n + 1];
    // pass 1: per-head max
    float m0 = -INFINITY, m1 = -INFINITY, m2 = -INFINITY, m3 = -INFINITY;
    for (int idx = start + lane; idx < end; idx += 64) {
        int se = csr_src[idx]; float ew = csr_ew[idx];
        float4 as = *(const float4*)(asrc_g + se * 4);
        float l0 = as.x + ad.x + ew * s0; l0 = l0 > 0.f ? l0 : 0.2f * l0; m0 = fmaxf(m0, l0);
        float l1 = as.y + ad.y + ew * s1; l1 = l1 > 0.f ? l1 : 0.2f * l1; m1 = fmaxf(m1, l1);
        float l2 = as.z + ad.z + ew * s2; l2 = l2 > 0.f ? l2 : 0.2f * l2; m2 = fmaxf(m2, l2);
        float l3 = as.w + ad.w + ew * s3; l3 = l3 > 0.f ? l3 : 0.2f * l3; m3 = fmaxf(m3, l3);
    }
#pragma unroll
    for (int d = 32; d; d >>= 1) {
        m0 = fmaxf(m0, __shfl_xor(m0, d)); m1 = fmaxf(m1, __shfl_xor(m1, d));
        m2 = fmaxf(m2, __shfl_xor(m2, d)); m3 = fmaxf(m3, __shfl_xor(m3, d));
    }
    // pass 2: exp + aggregate (channels across lanes; edges via shuffle broadcast)
    float den0 = 0.f, den1 = 0.f, den2 = 0.f, den3 = 0.f;
    float msg0 = 0.f, msg1 = 0.f;
    for (int base = start; base < end; base += 64) {
        int idx = base + lane;
        int se = 0; float e0 = 0.f, e1 = 0.f, e2 = 0.f, e3 = 0.f;
        if (idx < end) {
            se = csr_src[idx]; float ew = csr_ew[idx];
            float4 as = *(const float4*)(asrc_g + se * 4);
            float l0 = as.x + ad.x + ew * s0; l0 = l0 > 0.f ? l0 : 0.2f * l0; e0 = __expf(l0 - m0);
            float l1 = as.y + ad.y + ew * s1; l1 = l1 > 0.f ? l1 : 0.2f * l1; e1 = __expf(l1 - m1);
            float l2 = as.z + ad.z + ew * s2; l2 = l2 > 0.f ? l2 : 0.2f * l2; e2 = __expf(l2 - m2);
            float l3 = as.w + ad.w + ew * s3; l3 = l3 > 0.f ? l3 : 0.2f * l3; e3 = __expf(l3 - m3);
            den0 += e0; den1 += e1; den2 += e2; den3 += e3;
        }
        int cn = end - base; if (cn > 64) cn = 64;
        for (int e = 0; e < cn; ++e) {
            int sse = __shfl(se, e);
            float q0 = __shfl(e0, e), q1 = __shfl(e1, e), q2 = __shfl(e2, e), q3 = __shfl(e3, e);
            float w0 = (lane < 32) ? q0 : q1;
            float w1 = (lane < 32) ? q2 : q3;
            const float* hr = hg + sse * 128;
            msg0 += w0 * hr[lane];
            msg1 += w1 * hr[lane + 64];
        }
    }
#pragma unroll
    for (int d = 32; d; d >>= 1) {
        den0 += __shfl_xor(den0, d); den1 += __shfl_xor(den1, d);
        den2 += __shfl_xor(den2, d); den3 += __shfl_xor(den3, d);
    }
    float dd0 = (lane < 32) ? den0 : den1;
    float dd1 = (lane < 32) ? den2 : den3;
    msg0 /= (dd0 + 1e-16f);
    msg1 /= (dd1 + 1e-16f);
    float sums = msg0 + msg1;
    float t = __shfl_xor(sums, 32);
    float outc = 0.25f * (sums + t) + gat_bias[lane & 31];   // all lanes hold channel (lane&31)
    // projection: y[d] = b_proj[d] + sum_c outc[c] * W_proj[c][d], d = lane
    float acc = b_proj[lane];
#pragma unroll
    for (int c = 0; c < 32; c++) {
        float oc = __shfl(outc, c);
        acc += oc * wp[c * 64 + lane];
    }
    int b = g / TV, tt = g - b * TV;
    y[(((long)(b * NV + n)) * TV + tt) * 64 + lane] = acc;
}

// ---------------- K6: qkv (k,v all t; q only t=15) + attention + Wo + LN1 -> z1 ----------------
__global__ __launch_bounds__(256) void attn_kernel(const float* __restrict__ y, const float* __restrict__ Wqkv,
                                                   const float* __restrict__ bqkv, const float* __restrict__ Wo,
                                                   const float* __restrict__ bo, const float* __restrict__ ln1g,
                                                   const float* __restrict__ ln1b, float* __restrict__ z1) {
    __shared__ float yt[1024], kb[1024], vb[1024], wkv[8192], qv[64], pv[64], sc[64];
    int tid = threadIdx.x;
    int bn = blockIdx.x;
    const float* yb = y + (long)bn * 1024;
    for (int i = tid; i < 1024; i += 256) yt[i] = yb[i];
    for (int i = tid; i < 8192; i += 256) { int d = i >> 7, j = i & 127; wkv[i] = Wqkv[d * 192 + 64 + j]; }
    __syncthreads();
    // k, v for all t
    for (int o = tid; o < 2048; o += 256) {
        int t = o >> 7, j = o & 127;
        float a = bqkv[64 + j];
        const float* yrow = &yt[t * 64];
#pragma unroll
        for (int d = 0; d < 64; d++) a += yrow[d] * wkv[d * 128 + j];
        if (j < 64) kb[t * 64 + j] = a; else vb[t * 64 + (j - 64)] = a;
    }
    // q for t = 15
    if (tid < 64) {
        float a = bqkv[tid];
#pragma unroll
        for (int d = 0; d < 64; d++) a += yt[15 * 64 + d] * Wqkv[d * 192 + tid];
        qv[tid] = a;
    }
    __syncthreads();
    if (tid < 64) {
        int hh = tid >> 4, t = tid & 15;
        float s = 0.f;
#pragma unroll
        for (int dd = 0; dd < 16; dd++) s += qv[hh * 16 + dd] * kb[t * 64 + hh * 16 + dd];
        sc[tid] = s * 0.25f;
    }
    __syncthreads();
    if (tid < 64) {
        int hh = tid >> 4;
        float m = -INFINITY;
        for (int t = 0; t < 16; t++) m = fmaxf(m, sc[hh * 16 + t]);
        float den = 0.f;
        for (int t = 0; t < 16; t++) den += __expf(sc[hh * 16 + t] - m);
        pv[tid] = __expf(sc[tid] - m) / den;
    }
    __syncthreads();
    if (tid < 64) {
        int hh = tid >> 4;
        float ctx = 0.f;
#pragma unroll
        for (int t = 0; t < 16; t++) ctx += pv[hh * 16 + t] * vb[t * 64 + tid];
        sc[tid] = ctx;   // reuse as ctx buffer
    }
    __syncthreads();
    if (tid < 64) {
        float o = bo[tid];
#pragma unroll
        for (int j = 0; j < 64; j++) o += sc[j] * Wo[j * 64 + tid];
        float r = yt[15 * 64 + tid] + o;
        float sum = r, sq = r * r;
#pragma unroll
        for (int d = 32; d; d >>= 1) { sum += __shfl_xor(sum, d); sq += __shfl_xor(sq, d); }
        float mu = sum * (1.f / 64.f);
        float var = sq * (1.f / 64.f) - mu * mu;
        float zz = (r - mu) * rsqrtf(var + 1e-5f) * ln1g[tid] + ln1b[tid];
        z1[(long)bn * 64 + tid] = zz;
    }
}

// ---------------- K7: FF (chunked LDS GEMM) + LN2 -> out ----------------
__global__ __launch_bounds__(256) void ff_kernel(const float* __restrict__ z1, const float* __restrict__ W1,
                                                 const float* __restrict__ b1, const float* __restrict__ W2,
                                                 const float* __restrict__ b2, const float* __restrict__ ln2g,
                                                 const float* __restrict__ ln2b, float* __restrict__ out) {
    __shared__ float zt[16 * 64];    // 4KB
    __shared__ float ws[128 * 64];   // 32KB staging
    __shared__ float hb[16 * 128];   // 8KB
    int tid = threadIdx.x;
    int row0 = blockIdx.x * 16;
    for (int i = tid; i < 1024; i += 256) zt[i] = z1[(long)row0 * 64 + i];
    float acc[4] = {0.f, 0.f, 0.f, 0.f};
    int d = tid & 63, rq = tid >> 6;
    for (int c0 = 0; c0 < FFV; c0 += 128) {
        __syncthreads();
        for (int i = tid; i < 8192; i += 256) { int dd = i >> 7, fl = i & 127; ws[i] = W1[dd * FFV + c0 + fl]; }
        __syncthreads();
        for (int o = tid; o < 2048; o += 256) {
            int r = o >> 7, fl = o & 127;
            float a = b1[c0 + fl];
#pragma unroll
            for (int dd = 0; dd < 64; dd++) a += zt[r * 64 + dd] * ws[dd * 128 + fl];
            hb[o] = fmaxf(a, 0.f);
        }
        __syncthreads();
        for (int i = tid; i < 8192; i += 256) ws[i] = W2[c0 * 64 + i];
        __syncthreads();
#pragma unroll 4
        for (int fl = 0; fl < 128; fl++) {
            float w2v = ws[fl * 64 + d];
            acc[0] += hb[(rq + 0) * 128 + fl] * w2v;
            acc[1] += hb[(rq + 4) * 128 + fl] * w2v;
            acc[2] += hb[(rq + 8) * 128 + fl] * w2v;
            acc[3] += hb[(rq + 12) * 128 + fl] * w2v;
        }
    }
    float bb2 = b2[d];
#pragma unroll
    for (int k2 = 0; k2 < 4; k2++) {
        int r = rq + k2 * 4;
        float val = zt[r * 64 + d] + acc[k2] + bb2;
        float sum = val, sq = val * val;
#pragma unroll
        for (int dlt = 32; dlt; dlt >>= 1) { sum += __shfl_xor(sum, dlt); sq += __shfl_xor(sq, dlt); }
        float mu = sum * (1.f / 64.f);
        float var = sq * (1.f / 64.f) - mu * mu;
        float zz = (val - mu) * rsqrtf(var + 1e-5f) * ln2g[d] + ln2b[d];
        out[(long)(row0 + r) * 64 + d] = zz;
    }
}

extern "C" void kernel_launch(void* const* d_in, const int* in_sizes, int n_in,
                              void* d_out, int out_size, void* d_ws, size_t ws_size,
                              hipStream_t stream) {
    const float* x_seq      = (const float*)d_in[0];
    const int*   edge_index = (const int*)  d_in[1];
    const float* edge_weight= (const float*)d_in[2];
    const float* W_gat      = (const float*)d_in[3];
    const float* att_src    = (const float*)d_in[4];
    const float* att_dst    = (const float*)d_in[5];
    const float* W_edge     = (const float*)d_in[6];
    const float* att_edge   = (const float*)d_in[7];
    const float* gat_bias   = (const float*)d_in[8];
    const float* W_proj     = (const float*)d_in[9];
    const float* b_proj     = (const float*)d_in[10];
    const float* Wqkv       = (const float*)d_in[11];
    const float* bqkv       = (const float*)d_in[12];
    const float* Wo         = (const float*)d_in[13];
    const float* bo         = (const float*)d_in[14];
    const float* ln1g       = (const float*)d_in[15];
    const float* ln1b       = (const float*)d_in[16];
    const float* W1         = (const float*)d_in[17];
    const float* b1         = (const float*)d_in[18];
    const float* W2         = (const float*)d_in[19];
    const float* b2         = (const float*)d_in[20];
    const float* ln2g       = (const float*)d_in[21];
    const float* ln2b       = (const float*)d_in[22];
    float* outp = (float*)d_out;

    float* wsf = (float*)d_ws;
    float* h      = wsf + OFF_H;
    float* a_src  = wsf + OFF_ASRC;
    float* a_dst  = wsf + OFF_ADST;
    float* y      = wsf + OFF_Y;
    float* z1     = wsf + OFF_Z1;
    float* scal   = wsf + OFF_SCAL;
    int*   rowptr = (int*)(wsf + OFF_INTS);
    int*   cnt    = rowptr + 2001;
    int*   csr_src= cnt + 2000;
    float* csr_ew = wsf + OFF_CSREW;

    prep_kernel<<<1, 256, 0, stream>>>(edge_weight, W_edge, att_edge, scal);
    hipMemsetAsync(cnt, 0, NV * sizeof(int), stream);
    hist_kernel<<<(ETV + 255) / 256, 256, 0, stream>>>(edge_index, cnt);
    scan_kernel<<<1, 256, 0, stream>>>(cnt, rowptr, cnt);
    scatter_kernel<<<(ETV + 255) / 256, 256, 0, stream>>>(edge_index, edge_weight, scal, cnt, csr_src, csr_ew);
    gat_h_kernel<<<GV * NV / 4, 256, 0, stream>>>(x_seq, W_gat, att_src, att_dst, h, a_src, a_dst);
    gat_agg_kernel<<<GV * NV / 4, 256, 0, stream>>>(h, a_src, a_dst, rowptr, csr_src, csr_ew, scal,
                                                    gat_bias, W_proj, b_proj, y);
    attn_kernel<<<BV * NV, 256, 0, stream>>>(y, Wqkv, bqkv, Wo, bo, ln1g, ln1b, z1);
    ff_kernel<<<BV * NV / 16, 256, 0, stream>>>(z1, W1, b1, W2, b2, ln2g, ln2b, outp);
}

// Round 2
// 428.071 us; speedup vs baseline: 1.1468x; 1.1468x over previous
//
#include <hip/hip_runtime.h>
#include <math.h>

#define BV 2
#define TV 16
#define NV 2000
#define FIN 16
#define EV 32000
#define ETV 34000
#define GV 32
#define DD 64
#define FFV 2048

// workspace layout (float offsets)
#define OFF_H     0L          // h [32*2000*128] — dead after gat_agg; reused as ff accumulator
#define OFF_ASRC  8192000L
#define OFF_ADST  8448000L
#define OFF_Y     8704000L
#define OFF_Z1    12800000L
#define OFF_SCAL  13056000L   // [0]=ew_mean, [1..4]=s_h
#define OFF_INTS  13056016L   // rowptr[2001], cnt[2000], csr_src[34000]
#define OFF_CSREW 13094032L   // csr_ew[34000]

// ---------------- K0: ew_mean + per-head edge-attention scalars ----------------
__global__ void prep_kernel(const float* __restrict__ ew, const float* __restrict__ W_edge,
                            const float* __restrict__ att_edge, float* __restrict__ scal) {
    __shared__ float red[256];
    int tid = threadIdx.x;
    float s = 0.f;
    for (int i = tid; i < EV; i += 256) s += ew[i];
    red[tid] = s; __syncthreads();
    for (int d = 128; d > 0; d >>= 1) { if (tid < d) red[tid] += red[tid + d]; __syncthreads(); }
    if (tid == 0) scal[0] = red[0] / (float)EV;
    __syncthreads();
    float p = (tid < 128) ? W_edge[tid] * att_edge[tid] : 0.f;
    red[tid] = p; __syncthreads();
    if (tid < 4) {
        float t = 0.f;
        for (int c = 0; c < 32; c++) t += red[tid * 32 + c];
        scal[1 + tid] = t;
    }
}

// ---------------- K1: in-degree histogram (incl. self loops) ----------------
__global__ void hist_kernel(const int* __restrict__ edge_index, int* __restrict__ deg) {
    int e = blockIdx.x * 256 + threadIdx.x;
    if (e >= ETV) return;
    int dst = (e < EV) ? edge_index[EV + e] : (e - EV);
    atomicAdd(&deg[dst], 1);
}

// ---------------- K2: exclusive scan -> rowptr, copy -> cnt ----------------
__global__ void scan_kernel(const int* __restrict__ deg, int* __restrict__ rowptr, int* __restrict__ cnt) {
    __shared__ int tot[256];
    int tid = threadIdx.x;
    int base = tid * 8;
    int local[8]; int s = 0;
    for (int i = 0; i < 8; i++) { int v = (base + i < NV) ? deg[base + i] : 0; local[i] = s; s += v; }
    tot[tid] = s; __syncthreads();
    for (int d = 1; d < 256; d <<= 1) {
        int v = (tid >= d) ? tot[tid - d] : 0;
        __syncthreads();
        tot[tid] += v;
        __syncthreads();
    }
    int ex = tot[tid] - s;
    for (int i = 0; i < 8; i++) {
        int idx = base + i;
        if (idx < NV) { int rp = ex + local[i]; rowptr[idx] = rp; cnt[idx] = rp; }
    }
    if (tid == 255) rowptr[NV] = tot[255];
}

// ---------------- K3: scatter edges into CSR ----------------
__global__ void scatter_kernel(const int* __restrict__ edge_index, const float* __restrict__ edge_weight,
                               const float* __restrict__ scal, int* __restrict__ cnt,
                               int* __restrict__ csr_src, float* __restrict__ csr_ew) {
    int e = blockIdx.x * 256 + threadIdx.x;
    if (e >= ETV) return;
    int src, dst; float w;
    if (e < EV) { src = edge_index[e]; dst = edge_index[EV + e]; w = edge_weight[e]; }
    else        { src = dst = e - EV; w = scal[0]; }
    int pos = atomicAdd(&cnt[dst], 1);
    csr_src[pos] = src; csr_ew[pos] = w;
}

// ---------------- K4: h = x@W_gat, a_src, a_dst (one wave per (g,n) row) ----------------
__global__ __launch_bounds__(256) void gat_h_kernel(const float* __restrict__ x, const float* __restrict__ W_gat,
                                                    const float* __restrict__ att_src, const float* __restrict__ att_dst,
                                                    float* __restrict__ h, float* __restrict__ a_src, float* __restrict__ a_dst) {
    __shared__ float wg[16 * 128];
    int tid = threadIdx.x;
    for (int i = tid; i < 2048; i += 256) wg[i] = W_gat[i];
    __syncthreads();
    int wave = tid >> 6, lane = tid & 63;
    int row = blockIdx.x * 4 + wave;           // row = g*N + n
    const float* xr = x + (long)row * 16;
    float xv[16];
#pragma unroll
    for (int f = 0; f < 16; f++) xv[f] = xr[f];
    float h0 = 0.f, h1 = 0.f;
#pragma unroll
    for (int f = 0; f < 16; f++) { h0 += xv[f] * wg[f * 128 + lane]; h1 += xv[f] * wg[f * 128 + lane + 64]; }
    h[(long)row * 128 + lane] = h0;
    h[(long)row * 128 + lane + 64] = h1;
    float p0 = h0 * att_src[lane], p1 = h1 * att_src[lane + 64];
    float q0 = h0 * att_dst[lane], q1 = h1 * att_dst[lane + 64];
#pragma unroll
    for (int d = 1; d < 32; d <<= 1) {
        p0 += __shfl_xor(p0, d); p1 += __shfl_xor(p1, d);
        q0 += __shfl_xor(q0, d); q1 += __shfl_xor(q1, d);
    }
    if (lane == 0)  { a_src[row * 4 + 0] = p0; a_src[row * 4 + 2] = p1; a_dst[row * 4 + 0] = q0; a_dst[row * 4 + 2] = q1; }
    if (lane == 32) { a_src[row * 4 + 1] = p0; a_src[row * 4 + 3] = p1; a_dst[row * 4 + 1] = q0; a_dst[row * 4 + 3] = q1; }
}

// ---------------- K5: segment softmax + aggregation + head mean + W_proj -> y ----------------
__global__ __launch_bounds__(256) void gat_agg_kernel(const float* __restrict__ h, const float* __restrict__ a_src,
                                                      const float* __restrict__ a_dst, const int* __restrict__ rowptr,
                                                      const int* __restrict__ csr_src, const float* __restrict__ csr_ew,
                                                      const float* __restrict__ scal, const float* __restrict__ gat_bias,
                                                      const float* __restrict__ W_proj, const float* __restrict__ b_proj,
                                                      float* __restrict__ y) {
    __shared__ float wp[2048];
    int tid = threadIdx.x;
    for (int i = tid; i < 2048; i += 256) wp[i] = W_proj[i];
    __syncthreads();
    int lane = tid & 63, wave = tid >> 6;
    int w = blockIdx.x * 4 + wave;             // w = g*N + n
    int g = w / NV, n = w - g * NV;
    float s0 = scal[1], s1 = scal[2], s2 = scal[3], s3 = scal[4];
    const float4 ad = *(const float4*)(a_dst + (long)w * 4);
    const float* asrc_g = a_src + (long)g * NV * 4;
    const float* hg = h + (long)g * NV * 128;
    int start = rowptr[n], end = rowptr[n + 1];
    float m0 = -INFINITY, m1 = -INFINITY, m2 = -INFINITY, m3 = -INFINITY;
    for (int idx = start + lane; idx < end; idx += 64) {
        int se = csr_src[idx]; float ew = csr_ew[idx];
        float4 as = *(const float4*)(asrc_g + se * 4);
        float l0 = as.x + ad.x + ew * s0; l0 = l0 > 0.f ? l0 : 0.2f * l0; m0 = fmaxf(m0, l0);
        float l1 = as.y + ad.y + ew * s1; l1 = l1 > 0.f ? l1 : 0.2f * l1; m1 = fmaxf(m1, l1);
        float l2 = as.z + ad.z + ew * s2; l2 = l2 > 0.f ? l2 : 0.2f * l2; m2 = fmaxf(m2, l2);
        float l3 = as.w + ad.w + ew * s3; l3 = l3 > 0.f ? l3 : 0.2f * l3; m3 = fmaxf(m3, l3);
    }
#pragma unroll
    for (int d = 32; d; d >>= 1) {
        m0 = fmaxf(m0, __shfl_xor(m0, d)); m1 = fmaxf(m1, __shfl_xor(m1, d));
        m2 = fmaxf(m2, __shfl_xor(m2, d)); m3 = fmaxf(m3, __shfl_xor(m3, d));
    }
    float den0 = 0.f, den1 = 0.f, den2 = 0.f, den3 = 0.f;
    float msg0 = 0.f, msg1 = 0.f;
    for (int base = start; base < end; base += 64) {
        int idx = base + lane;
        int se = 0; float e0 = 0.f, e1 = 0.f, e2 = 0.f, e3 = 0.f;
        if (idx < end) {
            se = csr_src[idx]; float ew = csr_ew[idx];
            float4 as = *(const float4*)(asrc_g + se * 4);
            float l0 = as.x + ad.x + ew * s0; l0 = l0 > 0.f ? l0 : 0.2f * l0; e0 = __expf(l0 - m0);
            float l1 = as.y + ad.y + ew * s1; l1 = l1 > 0.f ? l1 : 0.2f * l1; e1 = __expf(l1 - m1);
            float l2 = as.z + ad.z + ew * s2; l2 = l2 > 0.f ? l2 : 0.2f * l2; e2 = __expf(l2 - m2);
            float l3 = as.w + ad.w + ew * s3; l3 = l3 > 0.f ? l3 : 0.2f * l3; e3 = __expf(l3 - m3);
            den0 += e0; den1 += e1; den2 += e2; den3 += e3;
        }
        int cn = end - base; if (cn > 64) cn = 64;
        for (int e = 0; e < cn; ++e) {
            int sse = __shfl(se, e);
            float q0 = __shfl(e0, e), q1 = __shfl(e1, e), q2 = __shfl(e2, e), q3 = __shfl(e3, e);
            float w0 = (lane < 32) ? q0 : q1;
            float w1 = (lane < 32) ? q2 : q3;
            const float* hr = hg + sse * 128;
            msg0 += w0 * hr[lane];
            msg1 += w1 * hr[lane + 64];
        }
    }
#pragma unroll
    for (int d = 32; d; d >>= 1) {
        den0 += __shfl_xor(den0, d); den1 += __shfl_xor(den1, d);
        den2 += __shfl_xor(den2, d); den3 += __shfl_xor(den3, d);
    }
    float dd0 = (lane < 32) ? den0 : den1;
    float dd1 = (lane < 32) ? den2 : den3;
    msg0 /= (dd0 + 1e-16f);
    msg1 /= (dd1 + 1e-16f);
    float sums = msg0 + msg1;
    float t = __shfl_xor(sums, 32);
    float outc = 0.25f * (sums + t) + gat_bias[lane & 31];
    float acc = b_proj[lane];
#pragma unroll
    for (int c = 0; c < 32; c++) {
        float oc = __shfl(outc, c);
        acc += oc * wp[c * 64 + lane];
    }
    int b = g / TV, tt = g - b * TV;
    y[(((long)(b * NV + n)) * TV + tt) * 64 + lane] = acc;
}

// ---------------- K6: qkv (k,v all t; q only t=15) + attention + Wo + LN1 -> z1 ----------------
__global__ __launch_bounds__(256) void attn_kernel(const float* __restrict__ y, const float* __restrict__ Wqkv,
                                                   const float* __restrict__ bqkv, const float* __restrict__ Wo,
                                                   const float* __restrict__ bo, const float* __restrict__ ln1g,
                                                   const float* __restrict__ ln1b, float* __restrict__ z1) {
    __shared__ float yt[1024], kb[1024], vb[1024], wkv[8192], qv[64], pv[64], sc[64];
    int tid = threadIdx.x;
    int bn = blockIdx.x;
    const float* yb = y + (long)bn * 1024;
    for (int i = tid; i < 1024; i += 256) yt[i] = yb[i];
    for (int i = tid; i < 8192; i += 256) { int d = i >> 7, j = i & 127; wkv[i] = Wqkv[d * 192 + 64 + j]; }
    __syncthreads();
    for (int o = tid; o < 2048; o += 256) {
        int t = o >> 7, j = o & 127;
        float a = bqkv[64 + j];
        const float* yrow = &yt[t * 64];
#pragma unroll
        for (int d = 0; d < 64; d++) a += yrow[d] * wkv[d * 128 + j];
        if (j < 64) kb[t * 64 + j] = a; else vb[t * 64 + (j - 64)] = a;
    }
    if (tid < 64) {
        float a = bqkv[tid];
#pragma unroll
        for (int d = 0; d < 64; d++) a += yt[15 * 64 + d] * Wqkv[d * 192 + tid];
        qv[tid] = a;
    }
    __syncthreads();
    if (tid < 64) {
        int hh = tid >> 4, t = tid & 15;
        float s = 0.f;
#pragma unroll
        for (int dd = 0; dd < 16; dd++) s += qv[hh * 16 + dd] * kb[t * 64 + hh * 16 + dd];
        sc[tid] = s * 0.25f;
    }
    __syncthreads();
    if (tid < 64) {
        int hh = tid >> 4;
        float m = -INFINITY;
        for (int t = 0; t < 16; t++) m = fmaxf(m, sc[hh * 16 + t]);
        float den = 0.f;
        for (int t = 0; t < 16; t++) den += __expf(sc[hh * 16 + t] - m);
        pv[tid] = __expf(sc[tid] - m) / den;
    }
    __syncthreads();
    if (tid < 64) {
        int hh = tid >> 4;
        float ctx = 0.f;
#pragma unroll
        for (int t = 0; t < 16; t++) ctx += pv[hh * 16 + t] * vb[t * 64 + tid];
        sc[tid] = ctx;
    }
    __syncthreads();
    if (tid < 64) {
        float o = bo[tid];
#pragma unroll
        for (int j = 0; j < 64; j++) o += sc[j] * Wo[j * 64 + tid];
        float r = yt[15 * 64 + tid] + o;
        float sum = r, sq = r * r;
#pragma unroll
        for (int d = 32; d; d >>= 1) { sum += __shfl_xor(sum, d); sq += __shfl_xor(sq, d); }
        float mu = sum * (1.f / 64.f);
        float var = sq * (1.f / 64.f) - mu * mu;
        float zz = (r - mu) * rsqrtf(var + 1e-5f) * ln1g[tid] + ln1b[tid];
        z1[(long)bn * 64 + tid] = zz;
    }
}

// ---------------- K7a: FF split-K partial GEMM -> atomic accumulate ----------------
// grid (250, 8): blockIdx.x = row block (16 rows), blockIdx.y = k-chunk (256 FF channels)
__global__ __launch_bounds__(256) void ff1_kernel(const float* __restrict__ z1, const float* __restrict__ W1,
                                                  const float* __restrict__ b1, const float* __restrict__ W2,
                                                  float* __restrict__ acc) {
    __shared__ float zt[16 * 64];    // 4KB
    __shared__ float ws[128 * 64];   // 32KB staging (W1 chunk then W2 chunk)
    __shared__ float hb[16 * 128];   // 8KB
    int tid = threadIdx.x;
    int row0 = blockIdx.x * 16;
    int c0 = blockIdx.y * 256;
    for (int i = tid; i < 1024; i += 256) zt[i] = z1[(long)row0 * 64 + i];
    float facc[4] = {0.f, 0.f, 0.f, 0.f};
    int d = tid & 63, rq = tid >> 6;
    for (int s = 0; s < 2; s++) {
        int cc = c0 + s * 128;
        __syncthreads();
        for (int i = tid; i < 8192; i += 256) { int dd = i >> 7, fl = i & 127; ws[i] = W1[dd * FFV + cc + fl]; }
        __syncthreads();
        for (int o = tid; o < 2048; o += 256) {
            int r = o >> 7, fl = o & 127;
            float a = b1[cc + fl];
#pragma unroll
            for (int dd = 0; dd < 64; dd++) a += zt[r * 64 + dd] * ws[dd * 128 + fl];
            hb[o] = fmaxf(a, 0.f);
        }
        __syncthreads();
        for (int i = tid; i < 8192; i += 256) ws[i] = W2[cc * 64 + i];
        __syncthreads();
#pragma unroll 4
        for (int fl = 0; fl < 128; fl++) {
            float w2v = ws[fl * 64 + d];
            facc[0] += hb[(rq + 0) * 128 + fl] * w2v;
            facc[1] += hb[(rq + 4) * 128 + fl] * w2v;
            facc[2] += hb[(rq + 8) * 128 + fl] * w2v;
            facc[3] += hb[(rq + 12) * 128 + fl] * w2v;
        }
    }
#pragma unroll
    for (int k2 = 0; k2 < 4; k2++) {
        int r = rq + k2 * 4;
        atomicAdd(&acc[(long)(row0 + r) * 64 + d], facc[k2]);
    }
}

// ---------------- K7b: residual + b2 + LN2 -> out (one wave per row) ----------------
__global__ __launch_bounds__(256) void ff2_kernel(const float* __restrict__ z1, const float* __restrict__ acc,
                                                  const float* __restrict__ b2, const float* __restrict__ ln2g,
                                                  const float* __restrict__ ln2b, float* __restrict__ out) {
    int tid = threadIdx.x;
    int lane = tid & 63, wave = tid >> 6;
    int row = blockIdx.x * 4 + wave;
    float val = z1[(long)row * 64 + lane] + acc[(long)row * 64 + lane] + b2[lane];
    float sum = val, sq = val * val;
#pragma unroll
    for (int dlt = 32; dlt; dlt >>= 1) { sum += __shfl_xor(sum, dlt); sq += __shfl_xor(sq, dlt); }
    float mu = sum * (1.f / 64.f);
    float var = sq * (1.f / 64.f) - mu * mu;
    float zz = (val - mu) * rsqrtf(var + 1e-5f) * ln2g[lane] + ln2b[lane];
    out[(long)row * 64 + lane] = zz;
}

extern "C" void kernel_launch(void* const* d_in, const int* in_sizes, int n_in,
                              void* d_out, int out_size, void* d_ws, size_t ws_size,
                              hipStream_t stream) {
    const float* x_seq      = (const float*)d_in[0];
    const int*   edge_index = (const int*)  d_in[1];
    const float* edge_weight= (const float*)d_in[2];
    const float* W_gat      = (const float*)d_in[3];
    const float* att_src    = (const float*)d_in[4];
    const float* att_dst    = (const float*)d_in[5];
    const float* W_edge     = (const float*)d_in[6];
    const float* att_edge   = (const float*)d_in[7];
    const float* gat_bias   = (const float*)d_in[8];
    const float* W_proj     = (const float*)d_in[9];
    const float* b_proj     = (const float*)d_in[10];
    const float* Wqkv       = (const float*)d_in[11];
    const float* bqkv       = (const float*)d_in[12];
    const float* Wo         = (const float*)d_in[13];
    const float* bo         = (const float*)d_in[14];
    const float* ln1g       = (const float*)d_in[15];
    const float* ln1b       = (const float*)d_in[16];
    const float* W1         = (const float*)d_in[17];
    const float* b1         = (const float*)d_in[18];
    const float* W2         = (const float*)d_in[19];
    const float* b2         = (const float*)d_in[20];
    const float* ln2g       = (const float*)d_in[21];
    const float* ln2b       = (const float*)d_in[22];
    float* outp = (float*)d_out;

    float* wsf = (float*)d_ws;
    float* h      = wsf + OFF_H;
    float* a_src  = wsf + OFF_ASRC;
    float* a_dst  = wsf + OFF_ADST;
    float* y      = wsf + OFF_Y;
    float* z1     = wsf + OFF_Z1;
    float* scal   = wsf + OFF_SCAL;
    int*   rowptr = (int*)(wsf + OFF_INTS);
    int*   cnt    = rowptr + 2001;
    int*   csr_src= cnt + 2000;
    float* csr_ew = wsf + OFF_CSREW;
    float* ffacc  = wsf + OFF_H;   // h is dead after gat_agg; reuse 1MB of it as FF accumulator

    prep_kernel<<<1, 256, 0, stream>>>(edge_weight, W_edge, att_edge, scal);
    hipMemsetAsync(cnt, 0, NV * sizeof(int), stream);
    hist_kernel<<<(ETV + 255) / 256, 256, 0, stream>>>(edge_index, cnt);
    scan_kernel<<<1, 256, 0, stream>>>(cnt, rowptr, cnt);
    scatter_kernel<<<(ETV + 255) / 256, 256, 0, stream>>>(edge_index, edge_weight, scal, cnt, csr_src, csr_ew);
    gat_h_kernel<<<GV * NV / 4, 256, 0, stream>>>(x_seq, W_gat, att_src, att_dst, h, a_src, a_dst);
    gat_agg_kernel<<<GV * NV / 4, 256, 0, stream>>>(h, a_src, a_dst, rowptr, csr_src, csr_ew, scal,
                                                    gat_bias, W_proj, b_proj, y);
    attn_kernel<<<BV * NV, 256, 0, stream>>>(y, Wqkv, bqkv, Wo, bo, ln1g, ln1b, z1);
    // h region is dead now; zero 1MB of it for the FF split-K accumulator (stream-ordered)
    hipMemsetAsync(ffacc, 0, (size_t)BV * NV * DD * sizeof(float), stream);
    dim3 ffgrid(BV * NV / 16, FFV / 256);
    ff1_kernel<<<ffgrid, 256, 0, stream>>>(z1, W1, b1, W2, ffacc);
    ff2_kernel<<<BV * NV / 4, 256, 0, stream>>>(z1, ffacc, b2, ln2g, ln2b, outp);
}

// Round 3
// 374.492 us; speedup vs baseline: 1.3109x; 1.1431x over previous
//
#include <hip/hip_runtime.h>
#include <math.h>

#define BV 2
#define TV 16
#define NV 2000
#define FIN 16
#define EV 32000
#define ETV 34000
#define GV 32
#define DD 64
#define FFV 2048

// workspace layout (float offsets)
#define OFF_H     0L          // h [32*2000*128] — dead after gat_agg; reused as ff accumulator
#define OFF_ASRC  8192000L
#define OFF_ADST  8448000L
#define OFF_Y     8704000L
#define OFF_Z1    12800000L
#define OFF_SCAL  13056000L   // [0]=ew_mean, [1..4]=s_h
#define OFF_INTS  13056016L   // rowptr[2001], cnt[2000], csr_src[34000]
#define OFF_CSREW 13094032L   // csr_ew[34000]

// ---------------- K0: ew_mean + per-head edge-attention scalars ----------------
__global__ void prep_kernel(const float* __restrict__ ew, const float* __restrict__ W_edge,
                            const float* __restrict__ att_edge, float* __restrict__ scal) {
    __shared__ float red[256];
    int tid = threadIdx.x;
    float s = 0.f;
    for (int i = tid; i < EV; i += 256) s += ew[i];
    red[tid] = s; __syncthreads();
    for (int d = 128; d > 0; d >>= 1) { if (tid < d) red[tid] += red[tid + d]; __syncthreads(); }
    if (tid == 0) scal[0] = red[0] / (float)EV;
    __syncthreads();
    float p = (tid < 128) ? W_edge[tid] * att_edge[tid] : 0.f;
    red[tid] = p; __syncthreads();
    if (tid < 4) {
        float t = 0.f;
        for (int c = 0; c < 32; c++) t += red[tid * 32 + c];
        scal[1 + tid] = t;
    }
}

// ---------------- K1: in-degree histogram (incl. self loops) ----------------
__global__ void hist_kernel(const int* __restrict__ edge_index, int* __restrict__ deg) {
    int e = blockIdx.x * 256 + threadIdx.x;
    if (e >= ETV) return;
    int dst = (e < EV) ? edge_index[EV + e] : (e - EV);
    atomicAdd(&deg[dst], 1);
}

// ---------------- K2: exclusive scan -> rowptr, copy -> cnt ----------------
__global__ void scan_kernel(const int* __restrict__ deg, int* __restrict__ rowptr, int* __restrict__ cnt) {
    __shared__ int tot[256];
    int tid = threadIdx.x;
    int base = tid * 8;
    int local[8]; int s = 0;
    for (int i = 0; i < 8; i++) { int v = (base + i < NV) ? deg[base + i] : 0; local[i] = s; s += v; }
    tot[tid] = s; __syncthreads();
    for (int d = 1; d < 256; d <<= 1) {
        int v = (tid >= d) ? tot[tid - d] : 0;
        __syncthreads();
        tot[tid] += v;
        __syncthreads();
    }
    int ex = tot[tid] - s;
    for (int i = 0; i < 8; i++) {
        int idx = base + i;
        if (idx < NV) { int rp = ex + local[i]; rowptr[idx] = rp; cnt[idx] = rp; }
    }
    if (tid == 255) rowptr[NV] = tot[255];
}

// ---------------- K3: scatter edges into CSR ----------------
__global__ void scatter_kernel(const int* __restrict__ edge_index, const float* __restrict__ edge_weight,
                               const float* __restrict__ scal, int* __restrict__ cnt,
                               int* __restrict__ csr_src, float* __restrict__ csr_ew) {
    int e = blockIdx.x * 256 + threadIdx.x;
    if (e >= ETV) return;
    int src, dst; float w;
    if (e < EV) { src = edge_index[e]; dst = edge_index[EV + e]; w = edge_weight[e]; }
    else        { src = dst = e - EV; w = scal[0]; }
    int pos = atomicAdd(&cnt[dst], 1);
    csr_src[pos] = src; csr_ew[pos] = w;
}

// ---------------- K4: h = x@W_gat, a_src, a_dst (one wave per (g,n) row) ----------------
__global__ __launch_bounds__(256) void gat_h_kernel(const float* __restrict__ x, const float* __restrict__ W_gat,
                                                    const float* __restrict__ att_src, const float* __restrict__ att_dst,
                                                    float* __restrict__ h, float* __restrict__ a_src, float* __restrict__ a_dst) {
    __shared__ float wg[16 * 128];
    int tid = threadIdx.x;
    for (int i = tid; i < 2048; i += 256) wg[i] = W_gat[i];
    __syncthreads();
    int wave = tid >> 6, lane = tid & 63;
    int row = blockIdx.x * 4 + wave;           // row = g*N + n
    const float* xr = x + (long)row * 16;
    float xv[16];
#pragma unroll
    for (int f = 0; f < 16; f++) xv[f] = xr[f];
    float h0 = 0.f, h1 = 0.f;
#pragma unroll
    for (int f = 0; f < 16; f++) { h0 += xv[f] * wg[f * 128 + lane]; h1 += xv[f] * wg[f * 128 + lane + 64]; }
    h[(long)row * 128 + lane] = h0;
    h[(long)row * 128 + lane + 64] = h1;
    float p0 = h0 * att_src[lane], p1 = h1 * att_src[lane + 64];
    float q0 = h0 * att_dst[lane], q1 = h1 * att_dst[lane + 64];
#pragma unroll
    for (int d = 1; d < 32; d <<= 1) {
        p0 += __shfl_xor(p0, d); p1 += __shfl_xor(p1, d);
        q0 += __shfl_xor(q0, d); q1 += __shfl_xor(q1, d);
    }
    if (lane == 0)  { a_src[row * 4 + 0] = p0; a_src[row * 4 + 2] = p1; a_dst[row * 4 + 0] = q0; a_dst[row * 4 + 2] = q1; }
    if (lane == 32) { a_src[row * 4 + 1] = p0; a_src[row * 4 + 3] = p1; a_dst[row * 4 + 1] = q0; a_dst[row * 4 + 3] = q1; }
}

// ---------------- K5: segment softmax + aggregation + head mean + W_proj -> y ----------------
// 16000 blocks. XCD-swizzled: xcd = bid&7 owns replicas [4*xcd, 4*xcd+4) so each
// XCD's L2 sees a ~1MB active h working set (sequential in j) instead of 32MB.
__global__ __launch_bounds__(256) void gat_agg_kernel(const float* __restrict__ h, const float* __restrict__ a_src,
                                                      const float* __restrict__ a_dst, const int* __restrict__ rowptr,
                                                      const int* __restrict__ csr_src, const float* __restrict__ csr_ew,
                                                      const float* __restrict__ scal, const float* __restrict__ gat_bias,
                                                      const float* __restrict__ W_proj, const float* __restrict__ b_proj,
                                                      float* __restrict__ y) {
    __shared__ float wp[2048];        // W_proj 32x64
    __shared__ int   ssrc[4][64];     // staged src indices per wave-chunk
    __shared__ float swt[4][4][64];   // staged exp-weights [wave][head][edge]
    __shared__ float sout[4][32];     // per-wave GAT output channels
    __shared__ int   mxch[4];
    int tid = threadIdx.x;
    for (int i = tid; i < 2048; i += 256) wp[i] = W_proj[i];
    int lane = tid & 63, wave = tid >> 6;
    int bid = blockIdx.x;
    int xcd = bid & 7, j = bid >> 3;          // j in [0,2000)
    int g = xcd * 4 + j / 500;
    int n = (j % 500) * 4 + wave;
    int w = g * NV + n;
    float s0 = scal[1], s1 = scal[2], s2 = scal[3], s3 = scal[4];
    const float4 ad = *(const float4*)(a_dst + (long)w * 4);
    const float* asrc_g = a_src + (long)g * NV * 4;
    const float* hg = h + (long)g * NV * 128;
    int start = rowptr[n], end = rowptr[n + 1];
    int nch = (end - start + 63) >> 6;
    if (lane == 0) mxch[wave] = nch;
    __syncthreads();
    int maxch = max(max(mxch[0], mxch[1]), max(mxch[2], mxch[3]));
    // single pass: exp (no max-shift; logits are O(1)), den accumulate, staged aggregation
    float den0 = 0.f, den1 = 0.f, den2 = 0.f, den3 = 0.f;
    float msg0 = 0.f, msg1 = 0.f;
    int hsel = lane >> 5;   // 0 or 1: which head within each 64-ch half this lane's channel belongs to
    for (int ch = 0; ch < maxch; ch++) {
        int base = start + ch * 64;
        int idx = base + lane;
        int se = 0; float e0 = 0.f, e1 = 0.f, e2 = 0.f, e3 = 0.f;
        if (idx < end) {
            se = csr_src[idx]; float ew = csr_ew[idx];
            float4 as = *(const float4*)(asrc_g + se * 4);
            float l0 = as.x + ad.x + ew * s0; l0 = l0 > 0.f ? l0 : 0.2f * l0; e0 = __expf(l0);
            float l1 = as.y + ad.y + ew * s1; l1 = l1 > 0.f ? l1 : 0.2f * l1; e1 = __expf(l1);
            float l2 = as.z + ad.z + ew * s2; l2 = l2 > 0.f ? l2 : 0.2f * l2; e2 = __expf(l2);
            float l3 = as.w + ad.w + ew * s3; l3 = l3 > 0.f ? l3 : 0.2f * l3; e3 = __expf(l3);
            den0 += e0; den1 += e1; den2 += e2; den3 += e3;
        }
        ssrc[wave][lane] = se;
        swt[wave][0][lane] = e0; swt[wave][1][lane] = e1;
        swt[wave][2][lane] = e2; swt[wave][3][lane] = e3;
        __syncthreads();
        int cn = end - base; cn = cn < 0 ? 0 : (cn > 64 ? 64 : cn);
        const float* wt0 = &swt[wave][hsel][0];
        const float* wt1 = &swt[wave][2 + hsel][0];
#pragma unroll 8
        for (int e = 0; e < cn; e++) {
            int sse = __builtin_amdgcn_readfirstlane(ssrc[wave][e]);
            const float* hr = hg + (long)sse * 128;
            msg0 += wt0[e] * hr[lane];
            msg1 += wt1[e] * hr[lane + 64];
        }
        __syncthreads();
    }
#pragma unroll
    for (int d = 32; d; d >>= 1) {
        den0 += __shfl_xor(den0, d); den1 += __shfl_xor(den1, d);
        den2 += __shfl_xor(den2, d); den3 += __shfl_xor(den3, d);
    }
    float dd0 = (lane < 32) ? den0 : den1;
    float dd1 = (lane < 32) ? den2 : den3;
    msg0 /= (dd0 + 1e-16f);
    msg1 /= (dd1 + 1e-16f);
    float sums = msg0 + msg1;
    float t = __shfl_xor(sums, 32);
    float outc = 0.25f * (sums + t) + gat_bias[lane & 31];   // channel (lane&31), dup across halves
    if (lane < 32) sout[wave][lane] = outc;
    __syncthreads();
    // projection: y[d] = b_proj[d] + sum_c outc[c] * W_proj[c][d], d = lane (independent FMAs)
    float acc = b_proj[lane];
#pragma unroll
    for (int c = 0; c < 32; c++) acc += sout[wave][c] * wp[c * 64 + lane];
    int b = g / TV, tt = g - b * TV;
    y[(((long)(b * NV + n)) * TV + tt) * 64 + lane] = acc;
}

// ---------------- K6: qkv (k,v all t; q only t=15) + attention + Wo + LN1 -> z1 ----------------
__global__ __launch_bounds__(256) void attn_kernel(const float* __restrict__ y, const float* __restrict__ Wqkv,
                                                   const float* __restrict__ bqkv, const float* __restrict__ Wo,
                                                   const float* __restrict__ bo, const float* __restrict__ ln1g,
                                                   const float* __restrict__ ln1b, float* __restrict__ z1) {
    __shared__ float yt[1024], kb[1024], vb[1024], wkv[8192], qv[64], pv[64], sc[64];
    int tid = threadIdx.x;
    int bn = blockIdx.x;
    const float* yb = y + (long)bn * 1024;
    for (int i = tid; i < 1024; i += 256) yt[i] = yb[i];
    for (int i = tid; i < 8192; i += 256) { int d = i >> 7, j = i & 127; wkv[i] = Wqkv[d * 192 + 64 + j]; }
    __syncthreads();
    for (int o = tid; o < 2048; o += 256) {
        int t = o >> 7, j = o & 127;
        float a = bqkv[64 + j];
        const float* yrow = &yt[t * 64];
#pragma unroll
        for (int d = 0; d < 64; d++) a += yrow[d] * wkv[d * 128 + j];
        if (j < 64) kb[t * 64 + j] = a; else vb[t * 64 + (j - 64)] = a;
    }
    if (tid < 64) {
        float a = bqkv[tid];
#pragma unroll
        for (int d = 0; d < 64; d++) a += yt[15 * 64 + d] * Wqkv[d * 192 + tid];
        qv[tid] = a;
    }
    __syncthreads();
    if (tid < 64) {
        int hh = tid >> 4, t = tid & 15;
        float s = 0.f;
#pragma unroll
        for (int dd = 0; dd < 16; dd++) s += qv[hh * 16 + dd] * kb[t * 64 + hh * 16 + dd];
        sc[tid] = s * 0.25f;
    }
    __syncthreads();
    if (tid < 64) {
        int hh = tid >> 4;
        float m = -INFINITY;
        for (int t = 0; t < 16; t++) m = fmaxf(m, sc[hh * 16 + t]);
        float den = 0.f;
        for (int t = 0; t < 16; t++) den += __expf(sc[hh * 16 + t] - m);
        pv[tid] = __expf(sc[tid] - m) / den;
    }
    __syncthreads();
    if (tid < 64) {
        int hh = tid >> 4;
        float ctx = 0.f;
#pragma unroll
        for (int t = 0; t < 16; t++) ctx += pv[hh * 16 + t] * vb[t * 64 + tid];
        sc[tid] = ctx;
    }
    __syncthreads();
    if (tid < 64) {
        float o = bo[tid];
#pragma unroll
        for (int j = 0; j < 64; j++) o += sc[j] * Wo[j * 64 + tid];
        float r = yt[15 * 64 + tid] + o;
        float sum = r, sq = r * r;
#pragma unroll
        for (int d = 32; d; d >>= 1) { sum += __shfl_xor(sum, d); sq += __shfl_xor(sq, d); }
        float mu = sum * (1.f / 64.f);
        float var = sq * (1.f / 64.f) - mu * mu;
        float zz = (r - mu) * rsqrtf(var + 1e-5f) * ln1g[tid] + ln1b[tid];
        z1[(long)bn * 64 + tid] = zz;
    }
}

// ---------------- K7a: FF split-K partial GEMM -> atomic accumulate ----------------
__global__ __launch_bounds__(256) void ff1_kernel(const float* __restrict__ z1, const float* __restrict__ W1,
                                                  const float* __restrict__ b1, const float* __restrict__ W2,
                                                  float* __restrict__ acc) {
    __shared__ float zt[16 * 64];
    __shared__ float ws[128 * 64];
    __shared__ float hb[16 * 128];
    int tid = threadIdx.x;
    int row0 = blockIdx.x * 16;
    int c0 = blockIdx.y * 256;
    for (int i = tid; i < 1024; i += 256) zt[i] = z1[(long)row0 * 64 + i];
    float facc[4] = {0.f, 0.f, 0.f, 0.f};
    int d = tid & 63, rq = tid >> 6;
    for (int s = 0; s < 2; s++) {
        int cc = c0 + s * 128;
        __syncthreads();
        for (int i = tid; i < 8192; i += 256) { int dd = i >> 7, fl = i & 127; ws[i] = W1[dd * FFV + cc + fl]; }
        __syncthreads();
        for (int o = tid; o < 2048; o += 256) {
            int r = o >> 7, fl = o & 127;
            float a = b1[cc + fl];
#pragma unroll
            for (int dd = 0; dd < 64; dd++) a += zt[r * 64 + dd] * ws[dd * 128 + fl];
            hb[o] = fmaxf(a, 0.f);
        }
        __syncthreads();
        for (int i = tid; i < 8192; i += 256) ws[i] = W2[cc * 64 + i];
        __syncthreads();
#pragma unroll 4
        for (int fl = 0; fl < 128; fl++) {
            float w2v = ws[fl * 64 + d];
            facc[0] += hb[(rq + 0) * 128 + fl] * w2v;
            facc[1] += hb[(rq + 4) * 128 + fl] * w2v;
            facc[2] += hb[(rq + 8) * 128 + fl] * w2v;
            facc[3] += hb[(rq + 12) * 128 + fl] * w2v;
        }
    }
#pragma unroll
    for (int k2 = 0; k2 < 4; k2++) {
        int r = rq + k2 * 4;
        atomicAdd(&acc[(long)(row0 + r) * 64 + d], facc[k2]);
    }
}

// ---------------- K7b: residual + b2 + LN2 -> out (one wave per row) ----------------
__global__ __launch_bounds__(256) void ff2_kernel(const float* __restrict__ z1, const float* __restrict__ acc,
                                                  const float* __restrict__ b2, const float* __restrict__ ln2g,
                                                  const float* __restrict__ ln2b, float* __restrict__ out) {
    int tid = threadIdx.x;
    int lane = tid & 63, wave = tid >> 6;
    int row = blockIdx.x * 4 + wave;
    float val = z1[(long)row * 64 + lane] + acc[(long)row * 64 + lane] + b2[lane];
    float sum = val, sq = val * val;
#pragma unroll
    for (int dlt = 32; dlt; dlt >>= 1) { sum += __shfl_xor(sum, dlt); sq += __shfl_xor(sq, dlt); }
    float mu = sum * (1.f / 64.f);
    float var = sq * (1.f / 64.f) - mu * mu;
    float zz = (val - mu) * rsqrtf(var + 1e-5f) * ln2g[lane] + ln2b[lane];
    out[(long)row * 64 + lane] = zz;
}

extern "C" void kernel_launch(void* const* d_in, const int* in_sizes, int n_in,
                              void* d_out, int out_size, void* d_ws, size_t ws_size,
                              hipStream_t stream) {
    const float* x_seq      = (const float*)d_in[0];
    const int*   edge_index = (const int*)  d_in[1];
    const float* edge_weight= (const float*)d_in[2];
    const float* W_gat      = (const float*)d_in[3];
    const float* att_src    = (const float*)d_in[4];
    const float* att_dst    = (const float*)d_in[5];
    const float* W_edge     = (const float*)d_in[6];
    const float* att_edge   = (const float*)d_in[7];
    const float* gat_bias   = (const float*)d_in[8];
    const float* W_proj     = (const float*)d_in[9];
    const float* b_proj     = (const float*)d_in[10];
    const float* Wqkv       = (const float*)d_in[11];
    const float* bqkv       = (const float*)d_in[12];
    const float* Wo         = (const float*)d_in[13];
    const float* bo         = (const float*)d_in[14];
    const float* ln1g       = (const float*)d_in[15];
    const float* ln1b       = (const float*)d_in[16];
    const float* W1         = (const float*)d_in[17];
    const float* b1         = (const float*)d_in[18];
    const float* W2         = (const float*)d_in[19];
    const float* b2         = (const float*)d_in[20];
    const float* ln2g       = (const float*)d_in[21];
    const float* ln2b       = (const float*)d_in[22];
    float* outp = (float*)d_out;

    float* wsf = (float*)d_ws;
    float* h      = wsf + OFF_H;
    float* a_src  = wsf + OFF_ASRC;
    float* a_dst  = wsf + OFF_ADST;
    float* y      = wsf + OFF_Y;
    float* z1     = wsf + OFF_Z1;
    float* scal   = wsf + OFF_SCAL;
    int*   rowptr = (int*)(wsf + OFF_INTS);
    int*   cnt    = rowptr + 2001;
    int*   csr_src= cnt + 2000;
    float* csr_ew = wsf + OFF_CSREW;
    float* ffacc  = wsf + OFF_H;   // h dead after gat_agg; reuse as FF accumulator

    prep_kernel<<<1, 256, 0, stream>>>(edge_weight, W_edge, att_edge, scal);
    hipMemsetAsync(cnt, 0, NV * sizeof(int), stream);
    hist_kernel<<<(ETV + 255) / 256, 256, 0, stream>>>(edge_index, cnt);
    scan_kernel<<<1, 256, 0, stream>>>(cnt, rowptr, cnt);
    scatter_kernel<<<(ETV + 255) / 256, 256, 0, stream>>>(edge_index, edge_weight, scal, cnt, csr_src, csr_ew);
    gat_h_kernel<<<GV * NV / 4, 256, 0, stream>>>(x_seq, W_gat, att_src, att_dst, h, a_src, a_dst);
    gat_agg_kernel<<<GV * NV / 4, 256, 0, stream>>>(h, a_src, a_dst, rowptr, csr_src, csr_ew, scal,
                                                    gat_bias, W_proj, b_proj, y);
    attn_kernel<<<BV * NV, 256, 0, stream>>>(y, Wqkv, bqkv, Wo, bo, ln1g, ln1b, z1);
    hipMemsetAsync(ffacc, 0, (size_t)BV * NV * DD * sizeof(float), stream);
    dim3 ffgrid(BV * NV / 16, FFV / 256);
    ff1_kernel<<<ffgrid, 256, 0, stream>>>(z1, W1, b1, W2, ffacc);
    ff2_kernel<<<BV * NV / 4, 256, 0, stream>>>(z1, ffacc, b2, ln2g, ln2b, outp);
}

// Round 4
// 351.911 us; speedup vs baseline: 1.3950x; 1.0642x over previous
//
#include <hip/hip_runtime.h>
#include <math.h>

#define BV 2
#define TV 16
#define NV 2000
#define FIN 16
#define EV 32000
#define ETV 34000
#define GV 32
#define DD 64
#define FFV 2048

// workspace layout (float offsets)
#define OFF_H     0L          // h [32*2000*128] — dead after gat_agg; reused as ff accumulator
#define OFF_ASRC  8192000L
#define OFF_ADST  8448000L
#define OFF_Y     8704000L
#define OFF_Z1    12800000L
#define OFF_SCAL  13056000L   // [0]=ew_mean, [1..4]=s_h
#define OFF_INTS  13056016L   // rowptr[2001], cnt[2000], csr_src[34000]
#define OFF_CSREW 13094032L   // csr_ew[34000]

// ---------------- K0: ew_mean + per-head edge-attention scalars ----------------
__global__ void prep_kernel(const float* __restrict__ ew, const float* __restrict__ W_edge,
                            const float* __restrict__ att_edge, float* __restrict__ scal) {
    __shared__ float red[256];
    int tid = threadIdx.x;
    float s = 0.f;
    for (int i = tid; i < EV; i += 256) s += ew[i];
    red[tid] = s; __syncthreads();
    for (int d = 128; d > 0; d >>= 1) { if (tid < d) red[tid] += red[tid + d]; __syncthreads(); }
    if (tid == 0) scal[0] = red[0] / (float)EV;
    __syncthreads();
    float p = (tid < 128) ? W_edge[tid] * att_edge[tid] : 0.f;
    red[tid] = p; __syncthreads();
    if (tid < 4) {
        float t = 0.f;
        for (int c = 0; c < 32; c++) t += red[tid * 32 + c];
        scal[1 + tid] = t;
    }
}

// ---------------- K1: in-degree histogram (incl. self loops) ----------------
__global__ void hist_kernel(const int* __restrict__ edge_index, int* __restrict__ deg) {
    int e = blockIdx.x * 256 + threadIdx.x;
    if (e >= ETV) return;
    int dst = (e < EV) ? edge_index[EV + e] : (e - EV);
    atomicAdd(&deg[dst], 1);
}

// ---------------- K2: exclusive scan -> rowptr, copy -> cnt ----------------
__global__ void scan_kernel(const int* __restrict__ deg, int* __restrict__ rowptr, int* __restrict__ cnt) {
    __shared__ int tot[256];
    int tid = threadIdx.x;
    int base = tid * 8;
    int local[8]; int s = 0;
    for (int i = 0; i < 8; i++) { int v = (base + i < NV) ? deg[base + i] : 0; local[i] = s; s += v; }
    tot[tid] = s; __syncthreads();
    for (int d = 1; d < 256; d <<= 1) {
        int v = (tid >= d) ? tot[tid - d] : 0;
        __syncthreads();
        tot[tid] += v;
        __syncthreads();
    }
    int ex = tot[tid] - s;
    for (int i = 0; i < 8; i++) {
        int idx = base + i;
        if (idx < NV) { int rp = ex + local[i]; rowptr[idx] = rp; cnt[idx] = rp; }
    }
    if (tid == 255) rowptr[NV] = tot[255];
}

// ---------------- K3: scatter edges into CSR ----------------
__global__ void scatter_kernel(const int* __restrict__ edge_index, const float* __restrict__ edge_weight,
                               const float* __restrict__ scal, int* __restrict__ cnt,
                               int* __restrict__ csr_src, float* __restrict__ csr_ew) {
    int e = blockIdx.x * 256 + threadIdx.x;
    if (e >= ETV) return;
    int src, dst; float w;
    if (e < EV) { src = edge_index[e]; dst = edge_index[EV + e]; w = edge_weight[e]; }
    else        { src = dst = e - EV; w = scal[0]; }
    int pos = atomicAdd(&cnt[dst], 1);
    csr_src[pos] = src; csr_ew[pos] = w;
}

// ---------------- K4: h = x@W_gat, a_src, a_dst (one wave per (g,n) row) ----------------
__global__ __launch_bounds__(256) void gat_h_kernel(const float* __restrict__ x, const float* __restrict__ W_gat,
                                                    const float* __restrict__ att_src, const float* __restrict__ att_dst,
                                                    float* __restrict__ h, float* __restrict__ a_src, float* __restrict__ a_dst) {
    __shared__ float wg[16 * 128];
    int tid = threadIdx.x;
    for (int i = tid; i < 2048; i += 256) wg[i] = W_gat[i];
    __syncthreads();
    int wave = tid >> 6, lane = tid & 63;
    int row = blockIdx.x * 4 + wave;           // row = g*N + n
    const float* xr = x + (long)row * 16;
    float xv[16];
#pragma unroll
    for (int f = 0; f < 16; f++) xv[f] = xr[f];
    float h0 = 0.f, h1 = 0.f;
#pragma unroll
    for (int f = 0; f < 16; f++) { h0 += xv[f] * wg[f * 128 + lane]; h1 += xv[f] * wg[f * 128 + lane + 64]; }
    h[(long)row * 128 + lane] = h0;
    h[(long)row * 128 + lane + 64] = h1;
    float p0 = h0 * att_src[lane], p1 = h1 * att_src[lane + 64];
    float q0 = h0 * att_dst[lane], q1 = h1 * att_dst[lane + 64];
#pragma unroll
    for (int d = 1; d < 32; d <<= 1) {
        p0 += __shfl_xor(p0, d); p1 += __shfl_xor(p1, d);
        q0 += __shfl_xor(q0, d); q1 += __shfl_xor(q1, d);
    }
    if (lane == 0)  { a_src[row * 4 + 0] = p0; a_src[row * 4 + 2] = p1; a_dst[row * 4 + 0] = q0; a_dst[row * 4 + 2] = q1; }
    if (lane == 32) { a_src[row * 4 + 1] = p0; a_src[row * 4 + 3] = p1; a_dst[row * 4 + 1] = q0; a_dst[row * 4 + 3] = q1; }
}

// ---------------- K5: segment softmax + aggregation + head mean + W_proj -> y ----------------
// 16000 blocks, XCD-swizzled. One wave per (g,n). Lanes: half=lane>>5 picks edge parity,
// c=lane&31 picks 4 channels (4c..4c+3, all in head c>>3). float4 h-gather: one
// global_load_dwordx4 per half-wave covers a full 512B h row. Per-wave LDS staging,
// no __syncthreads in the loop (wave-synchronous; LDS is in-order within a wave).
__global__ __launch_bounds__(256) void gat_agg_kernel(const float* __restrict__ h, const float* __restrict__ a_src,
                                                      const float* __restrict__ a_dst, const int* __restrict__ rowptr,
                                                      const int* __restrict__ csr_src, const float* __restrict__ csr_ew,
                                                      const float* __restrict__ scal, const float* __restrict__ gat_bias,
                                                      const float* __restrict__ W_proj, const float* __restrict__ b_proj,
                                                      float* __restrict__ y) {
    __shared__ float wp[2048];        // W_proj 32x64
    __shared__ int   ssrc[4][64];     // staged src indices per wave
    __shared__ float swt[4][4][65];   // staged exp-weights [wave][head][edge], padded
    __shared__ float sout[4][32];     // per-wave GAT output channels
    int tid = threadIdx.x;
    for (int i = tid; i < 2048; i += 256) wp[i] = W_proj[i];
    __syncthreads();
    int lane = tid & 63, wave = tid >> 6;
    int bid = blockIdx.x;
    int xcd = bid & 7, j = bid >> 3;          // j in [0,2000)
    int g = xcd * 4 + j / 500;
    int n = (j % 500) * 4 + wave;
    int w = g * NV + n;
    float s0 = scal[1], s1 = scal[2], s2 = scal[3], s3 = scal[4];
    const float4 ad = *(const float4*)(a_dst + (long)w * 4);
    const float* asrc_g = a_src + (long)g * NV * 4;
    const float* hg = h + (long)g * NV * 128;
    int start = rowptr[n], end = rowptr[n + 1];
    int half = lane >> 5, c = lane & 31;
    int hsel = c >> 3;                 // head of this lane's 4 channels
    float den0 = 0.f, den1 = 0.f, den2 = 0.f, den3 = 0.f;
    float4 msg = {0.f, 0.f, 0.f, 0.f};
    for (int base = start; base < end; base += 64) {
        int idx = base + lane;
        int se = 0; float e0 = 0.f, e1 = 0.f, e2 = 0.f, e3 = 0.f;
        if (idx < end) {
            se = csr_src[idx]; float ew = csr_ew[idx];
            float4 as = *(const float4*)(asrc_g + se * 4);
            float l0 = as.x + ad.x + ew * s0; l0 = l0 > 0.f ? l0 : 0.2f * l0; e0 = __expf(l0);
            float l1 = as.y + ad.y + ew * s1; l1 = l1 > 0.f ? l1 : 0.2f * l1; e1 = __expf(l1);
            float l2 = as.z + ad.z + ew * s2; l2 = l2 > 0.f ? l2 : 0.2f * l2; e2 = __expf(l2);
            float l3 = as.w + ad.w + ew * s3; l3 = l3 > 0.f ? l3 : 0.2f * l3; e3 = __expf(l3);
            den0 += e0; den1 += e1; den2 += e2; den3 += e3;
        }
        ssrc[wave][lane] = se;
        swt[wave][0][lane] = e0; swt[wave][1][lane] = e1;
        swt[wave][2][lane] = e2; swt[wave][3][lane] = e3;
        __builtin_amdgcn_wave_barrier();   // order staging writes before reads (in-order LDS within wave)
        int cn = end - base; if (cn > 64) cn = 64;
        int npairs = (cn + 1) >> 1;        // this half handles slots 2i+half; extra slot has weight 0
#pragma unroll 4
        for (int i = 0; i < npairs; i++) {
            int slot = 2 * i + half;
            int sse = ssrc[wave][slot];
            float wt = swt[wave][hsel][slot];
            const float4 hv = *(const float4*)(hg + (long)sse * 128 + c * 4);
            msg.x += wt * hv.x; msg.y += wt * hv.y; msg.z += wt * hv.z; msg.w += wt * hv.w;
        }
        __builtin_amdgcn_wave_barrier();   // keep next chunk's staging after these reads
    }
    // full-wave den reduction (all lanes end with all four head denominators)
#pragma unroll
    for (int d = 32; d; d >>= 1) {
        den0 += __shfl_xor(den0, d); den1 += __shfl_xor(den1, d);
        den2 += __shfl_xor(den2, d); den3 += __shfl_xor(den3, d);
    }
    float denh = (hsel == 0) ? den0 : (hsel == 1) ? den1 : (hsel == 2) ? den2 : den3;
    float inv = 1.f / (denh + 1e-16f);
    msg.x *= inv; msg.y *= inv; msg.z *= inv; msg.w *= inv;
    // combine edge-parity halves (same channels, same head)
    msg.x += __shfl_xor(msg.x, 32); msg.y += __shfl_xor(msg.y, 32);
    msg.z += __shfl_xor(msg.z, 32); msg.w += __shfl_xor(msg.w, 32);
    // head mean: heads live in bits 3..4 of c
    msg.x += __shfl_xor(msg.x, 8);  msg.y += __shfl_xor(msg.y, 8);
    msg.z += __shfl_xor(msg.z, 8);  msg.w += __shfl_xor(msg.w, 8);
    msg.x += __shfl_xor(msg.x, 16); msg.y += __shfl_xor(msg.y, 16);
    msg.z += __shfl_xor(msg.z, 16); msg.w += __shfl_xor(msg.w, 16);
    if (half == 0 && c < 8) {
        sout[wave][c * 4 + 0] = 0.25f * msg.x + gat_bias[c * 4 + 0];
        sout[wave][c * 4 + 1] = 0.25f * msg.y + gat_bias[c * 4 + 1];
        sout[wave][c * 4 + 2] = 0.25f * msg.z + gat_bias[c * 4 + 2];
        sout[wave][c * 4 + 3] = 0.25f * msg.w + gat_bias[c * 4 + 3];
    }
    __builtin_amdgcn_wave_barrier();
    // projection: y[d] = b_proj[d] + sum_c sout[c] * W_proj[c][d], d = lane
    float acc = b_proj[lane];
#pragma unroll
    for (int cc = 0; cc < 32; cc++) acc += sout[wave][cc] * wp[cc * 64 + lane];
    int b = g / TV, tt = g - b * TV;
    y[(((long)(b * NV + n)) * TV + tt) * 64 + lane] = acc;
}

// ---------------- K6: qkv (k,v all t; q only t=15) + attention + Wo + LN1 -> z1 ----------------
__global__ __launch_bounds__(256) void attn_kernel(const float* __restrict__ y, const float* __restrict__ Wqkv,
                                                   const float* __restrict__ bqkv, const float* __restrict__ Wo,
                                                   const float* __restrict__ bo, const float* __restrict__ ln1g,
                                                   const float* __restrict__ ln1b, float* __restrict__ z1) {
    __shared__ float yt[1024], kb[1024], vb[1024], wkv[8192], qv[64], pv[64], sc[64];
    int tid = threadIdx.x;
    int bn = blockIdx.x;
    const float* yb = y + (long)bn * 1024;
    for (int i = tid; i < 1024; i += 256) yt[i] = yb[i];
    for (int i = tid; i < 8192; i += 256) { int d = i >> 7, j = i & 127; wkv[i] = Wqkv[d * 192 + 64 + j]; }
    __syncthreads();
    for (int o = tid; o < 2048; o += 256) {
        int t = o >> 7, j = o & 127;
        float a = bqkv[64 + j];
        const float* yrow = &yt[t * 64];
#pragma unroll
        for (int d = 0; d < 64; d++) a += yrow[d] * wkv[d * 128 + j];
        if (j < 64) kb[t * 64 + j] = a; else vb[t * 64 + (j - 64)] = a;
    }
    if (tid < 64) {
        float a = bqkv[tid];
#pragma unroll
        for (int d = 0; d < 64; d++) a += yt[15 * 64 + d] * Wqkv[d * 192 + tid];
        qv[tid] = a;
    }
    __syncthreads();
    if (tid < 64) {
        int hh = tid >> 4, t = tid & 15;
        float s = 0.f;
#pragma unroll
        for (int dd = 0; dd < 16; dd++) s += qv[hh * 16 + dd] * kb[t * 64 + hh * 16 + dd];
        sc[tid] = s * 0.25f;
    }
    __syncthreads();
    if (tid < 64) {
        int hh = tid >> 4;
        float m = -INFINITY;
        for (int t = 0; t < 16; t++) m = fmaxf(m, sc[hh * 16 + t]);
        float den = 0.f;
        for (int t = 0; t < 16; t++) den += __expf(sc[hh * 16 + t] - m);
        pv[tid] = __expf(sc[tid] - m) / den;
    }
    __syncthreads();
    if (tid < 64) {
        int hh = tid >> 4;
        float ctx = 0.f;
#pragma unroll
        for (int t = 0; t < 16; t++) ctx += pv[hh * 16 + t] * vb[t * 64 + tid];
        sc[tid] = ctx;
    }
    __syncthreads();
    if (tid < 64) {
        float o = bo[tid];
#pragma unroll
        for (int j = 0; j < 64; j++) o += sc[j] * Wo[j * 64 + tid];
        float r = yt[15 * 64 + tid] + o;
        float sum = r, sq = r * r;
#pragma unroll
        for (int d = 32; d; d >>= 1) { sum += __shfl_xor(sum, d); sq += __shfl_xor(sq, d); }
        float mu = sum * (1.f / 64.f);
        float var = sq * (1.f / 64.f) - mu * mu;
        float zz = (r - mu) * rsqrtf(var + 1e-5f) * ln1g[tid] + ln1b[tid];
        z1[(long)bn * 64 + tid] = zz;
    }
}

// ---------------- K7a: FF split-K partial GEMM -> atomic accumulate ----------------
__global__ __launch_bounds__(256) void ff1_kernel(const float* __restrict__ z1, const float* __restrict__ W1,
                                                  const float* __restrict__ b1, const float* __restrict__ W2,
                                                  float* __restrict__ acc) {
    __shared__ float zt[16 * 64];
    __shared__ float ws[128 * 64];
    __shared__ float hb[16 * 128];
    int tid = threadIdx.x;
    int row0 = blockIdx.x * 16;
    int c0 = blockIdx.y * 256;
    for (int i = tid; i < 1024; i += 256) zt[i] = z1[(long)row0 * 64 + i];
    float facc[4] = {0.f, 0.f, 0.f, 0.f};
    int d = tid & 63, rq = tid >> 6;
    for (int s = 0; s < 2; s++) {
        int cc = c0 + s * 128;
        __syncthreads();
        for (int i = tid; i < 8192; i += 256) { int dd = i >> 7, fl = i & 127; ws[i] = W1[dd * FFV + cc + fl]; }
        __syncthreads();
        for (int o = tid; o < 2048; o += 256) {
            int r = o >> 7, fl = o & 127;
            float a = b1[cc + fl];
#pragma unroll
            for (int dd = 0; dd < 64; dd++) a += zt[r * 64 + dd] * ws[dd * 128 + fl];
            hb[o] = fmaxf(a, 0.f);
        }
        __syncthreads();
        for (int i = tid; i < 8192; i += 256) ws[i] = W2[cc * 64 + i];
        __syncthreads();
#pragma unroll 4
        for (int fl = 0; fl < 128; fl++) {
            float w2v = ws[fl * 64 + d];
            facc[0] += hb[(rq + 0) * 128 + fl] * w2v;
            facc[1] += hb[(rq + 4) * 128 + fl] * w2v;
            facc[2] += hb[(rq + 8) * 128 + fl] * w2v;
            facc[3] += hb[(rq + 12) * 128 + fl] * w2v;
        }
    }
#pragma unroll
    for (int k2 = 0; k2 < 4; k2++) {
        int r = rq + k2 * 4;
        atomicAdd(&acc[(long)(row0 + r) * 64 + d], facc[k2]);
    }
}

// ---------------- K7b: residual + b2 + LN2 -> out (one wave per row) ----------------
__global__ __launch_bounds__(256) void ff2_kernel(const float* __restrict__ z1, const float* __restrict__ acc,
                                                  const float* __restrict__ b2, const float* __restrict__ ln2g,
                                                  const float* __restrict__ ln2b, float* __restrict__ out) {
    int tid = threadIdx.x;
    int lane = tid & 63, wave = tid >> 6;
    int row = blockIdx.x * 4 + wave;
    float val = z1[(long)row * 64 + lane] + acc[(long)row * 64 + lane] + b2[lane];
    float sum = val, sq = val * val;
#pragma unroll
    for (int dlt = 32; dlt; dlt >>= 1) { sum += __shfl_xor(sum, dlt); sq += __shfl_xor(sq, dlt); }
    float mu = sum * (1.f / 64.f);
    float var = sq * (1.f / 64.f) - mu * mu;
    float zz = (val - mu) * rsqrtf(var + 1e-5f) * ln2g[lane] + ln2b[lane];
    out[(long)row * 64 + lane] = zz;
}

extern "C" void kernel_launch(void* const* d_in, const int* in_sizes, int n_in,
                              void* d_out, int out_size, void* d_ws, size_t ws_size,
                              hipStream_t stream) {
    const float* x_seq      = (const float*)d_in[0];
    const int*   edge_index = (const int*)  d_in[1];
    const float* edge_weight= (const float*)d_in[2];
    const float* W_gat      = (const float*)d_in[3];
    const float* att_src    = (const float*)d_in[4];
    const float* att_dst    = (const float*)d_in[5];
    const float* W_edge     = (const float*)d_in[6];
    const float* att_edge   = (const float*)d_in[7];
    const float* gat_bias   = (const float*)d_in[8];
    const float* W_proj     = (const float*)d_in[9];
    const float* b_proj     = (const float*)d_in[10];
    const float* Wqkv       = (const float*)d_in[11];
    const float* bqkv       = (const float*)d_in[12];
    const float* Wo         = (const float*)d_in[13];
    const float* bo         = (const float*)d_in[14];
    const float* ln1g       = (const float*)d_in[15];
    const float* ln1b       = (const float*)d_in[16];
    const float* W1         = (const float*)d_in[17];
    const float* b1         = (const float*)d_in[18];
    const float* W2         = (const float*)d_in[19];
    const float* b2         = (const float*)d_in[20];
    const float* ln2g       = (const float*)d_in[21];
    const float* ln2b       = (const float*)d_in[22];
    float* outp = (float*)d_out;

    float* wsf = (float*)d_ws;
    float* h      = wsf + OFF_H;
    float* a_src  = wsf + OFF_ASRC;
    float* a_dst  = wsf + OFF_ADST;
    float* y      = wsf + OFF_Y;
    float* z1     = wsf + OFF_Z1;
    float* scal   = wsf + OFF_SCAL;
    int*   rowptr = (int*)(wsf + OFF_INTS);
    int*   cnt    = rowptr + 2001;
    int*   csr_src= cnt + 2000;
    float* csr_ew = wsf + OFF_CSREW;
    float* ffacc  = wsf + OFF_H;   // h dead after gat_agg; reuse as FF accumulator

    prep_kernel<<<1, 256, 0, stream>>>(edge_weight, W_edge, att_edge, scal);
    hipMemsetAsync(cnt, 0, NV * sizeof(int), stream);
    hist_kernel<<<(ETV + 255) / 256, 256, 0, stream>>>(edge_index, cnt);
    scan_kernel<<<1, 256, 0, stream>>>(cnt, rowptr, cnt);
    scatter_kernel<<<(ETV + 255) / 256, 256, 0, stream>>>(edge_index, edge_weight, scal, cnt, csr_src, csr_ew);
    gat_h_kernel<<<GV * NV / 4, 256, 0, stream>>>(x_seq, W_gat, att_src, att_dst, h, a_src, a_dst);
    gat_agg_kernel<<<GV * NV / 4, 256, 0, stream>>>(h, a_src, a_dst, rowptr, csr_src, csr_ew, scal,
                                                    gat_bias, W_proj, b_proj, y);
    attn_kernel<<<BV * NV, 256, 0, stream>>>(y, Wqkv, bqkv, Wo, bo, ln1g, ln1b, z1);
    hipMemsetAsync(ffacc, 0, (size_t)BV * NV * DD * sizeof(float), stream);
    dim3 ffgrid(BV * NV / 16, FFV / 256);
    ff1_kernel<<<ffgrid, 256, 0, stream>>>(z1, W1, b1, W2, ffacc);
    ff2_kernel<<<BV * NV / 4, 256, 0, stream>>>(z1, ffacc, b2, ln2g, ln2b, outp);
}

// Round 6
// 309.039 us; speedup vs baseline: 1.5885x; 1.1387x over previous
//
#include <hip/hip_runtime.h>
#include <math.h>

#define BV 2
#define TV 16
#define NV 2000
#define FIN 16
#define EV 32000
#define ETV 34000
#define GV 32
#define DD 64
#define FFV 2048

// workspace layout (float offsets)
#define OFF_H     0L          // h [32*2000*128] — dead after gat_agg; reused for packed bf16 W1/W2 + probe tbl
#define OFF_ASRC  8192000L
#define OFF_ADST  8448000L
#define OFF_Y     8704000L
#define OFF_Z1    12800000L
#define OFF_SCAL  13056000L   // [0]=ew_mean, [1..4]=s_h
#define OFF_INTS  13056016L   // rowptr[2001], cnt[2000], csr_src[34000]
#define OFF_CSREW 13094032L   // csr_ew[34000]
#define OFF_TBL   140000L     // int tbl[544] inside dead h region (after pw1/pw2 = 131072 floats)

typedef __attribute__((ext_vector_type(8))) short bf16x8;
typedef __attribute__((ext_vector_type(4))) float f32x4;

__device__ __forceinline__ short f2bf(float f) {
    union { float f; unsigned u; } v; v.f = f;
    unsigned r = v.u + 0x7FFFu + ((v.u >> 16) & 1u);   // round-to-nearest-even
    return (short)(r >> 16);
}

// ---------------- K0: ew_mean + per-head edge-attention scalars ----------------
__global__ void prep_kernel(const float* __restrict__ ew, const float* __restrict__ W_edge,
                            const float* __restrict__ att_edge, float* __restrict__ scal) {
    __shared__ float red[256];
    int tid = threadIdx.x;
    float s = 0.f;
    for (int i = tid; i < EV; i += 256) s += ew[i];
    red[tid] = s; __syncthreads();
    for (int d = 128; d > 0; d >>= 1) { if (tid < d) red[tid] += red[tid + d]; __syncthreads(); }
    if (tid == 0) scal[0] = red[0] / (float)EV;
    __syncthreads();
    float p = (tid < 128) ? W_edge[tid] * att_edge[tid] : 0.f;
    red[tid] = p; __syncthreads();
    if (tid < 4) {
        float t = 0.f;
        for (int c = 0; c < 32; c++) t += red[tid * 32 + c];
        scal[1 + tid] = t;
    }
}

// ---------------- K1: in-degree histogram (incl. self loops) ----------------
__global__ void hist_kernel(const int* __restrict__ edge_index, int* __restrict__ deg) {
    int e = blockIdx.x * 256 + threadIdx.x;
    if (e >= ETV) return;
    int dst = (e < EV) ? edge_index[EV + e] : (e - EV);
    atomicAdd(&deg[dst], 1);
}

// ---------------- K2: exclusive scan -> rowptr, copy -> cnt ----------------
__global__ void scan_kernel(const int* __restrict__ deg, int* __restrict__ rowptr, int* __restrict__ cnt) {
    __shared__ int tot[256];
    int tid = threadIdx.x;
    int base = tid * 8;
    int local[8]; int s = 0;
    for (int i = 0; i < 8; i++) { int v = (base + i < NV) ? deg[base + i] : 0; local[i] = s; s += v; }
    tot[tid] = s; __syncthreads();
    for (int d = 1; d < 256; d <<= 1) {
        int v = (tid >= d) ? tot[tid - d] : 0;
        __syncthreads();
        tot[tid] += v;
        __syncthreads();
    }
    int ex = tot[tid] - s;
    for (int i = 0; i < 8; i++) {
        int idx = base + i;
        if (idx < NV) { int rp = ex + local[i]; rowptr[idx] = rp; cnt[idx] = rp; }
    }
    if (tid == 255) rowptr[NV] = tot[255];
}

// ---------------- K3: scatter edges into CSR ----------------
__global__ void scatter_kernel(const int* __restrict__ edge_index, const float* __restrict__ edge_weight,
                               const float* __restrict__ scal, int* __restrict__ cnt,
                               int* __restrict__ csr_src, float* __restrict__ csr_ew) {
    int e = blockIdx.x * 256 + threadIdx.x;
    if (e >= ETV) return;
    int src, dst; float w;
    if (e < EV) { src = edge_index[e]; dst = edge_index[EV + e]; w = edge_weight[e]; }
    else        { src = dst = e - EV; w = scal[0]; }
    int pos = atomicAdd(&cnt[dst], 1);
    csr_src[pos] = src; csr_ew[pos] = w;
}

// ---------------- K4: h = x@W_gat, a_src, a_dst (one wave per (g,n) row) ----------------
__global__ __launch_bounds__(256) void gat_h_kernel(const float* __restrict__ x, const float* __restrict__ W_gat,
                                                    const float* __restrict__ att_src, const float* __restrict__ att_dst,
                                                    float* __restrict__ h, float* __restrict__ a_src, float* __restrict__ a_dst) {
    __shared__ float wg[16 * 128];
    int tid = threadIdx.x;
    for (int i = tid; i < 2048; i += 256) wg[i] = W_gat[i];
    __syncthreads();
    int wave = tid >> 6, lane = tid & 63;
    int row = blockIdx.x * 4 + wave;           // row = g*N + n
    const float* xr = x + (long)row * 16;
    float xv[16];
#pragma unroll
    for (int f = 0; f < 16; f++) xv[f] = xr[f];
    float h0 = 0.f, h1 = 0.f;
#pragma unroll
    for (int f = 0; f < 16; f++) { h0 += xv[f] * wg[f * 128 + lane]; h1 += xv[f] * wg[f * 128 + lane + 64]; }
    h[(long)row * 128 + lane] = h0;
    h[(long)row * 128 + lane + 64] = h1;
    float p0 = h0 * att_src[lane], p1 = h1 * att_src[lane + 64];
    float q0 = h0 * att_dst[lane], q1 = h1 * att_dst[lane + 64];
#pragma unroll
    for (int d = 1; d < 32; d <<= 1) {
        p0 += __shfl_xor(p0, d); p1 += __shfl_xor(p1, d);
        q0 += __shfl_xor(q0, d); q1 += __shfl_xor(q1, d);
    }
    if (lane == 0)  { a_src[row * 4 + 0] = p0; a_src[row * 4 + 2] = p1; a_dst[row * 4 + 0] = q0; a_dst[row * 4 + 2] = q1; }
    if (lane == 32) { a_src[row * 4 + 1] = p0; a_src[row * 4 + 3] = p1; a_dst[row * 4 + 1] = q0; a_dst[row * 4 + 3] = q1; }
}

// ---------------- K5: segment softmax + aggregation + head mean + W_proj -> y ----------------
__global__ __launch_bounds__(256) void gat_agg_kernel(const float* __restrict__ h, const float* __restrict__ a_src,
                                                      const float* __restrict__ a_dst, const int* __restrict__ rowptr,
                                                      const int* __restrict__ csr_src, const float* __restrict__ csr_ew,
                                                      const float* __restrict__ scal, const float* __restrict__ gat_bias,
                                                      const float* __restrict__ W_proj, const float* __restrict__ b_proj,
                                                      float* __restrict__ y) {
    __shared__ float wp[2048];        // W_proj 32x64
    __shared__ int   ssrc[4][64];     // staged src indices per wave
    __shared__ float swt[4][4][65];   // staged exp-weights [wave][head][edge], padded
    __shared__ float sout[4][32];     // per-wave GAT output channels
    int tid = threadIdx.x;
    for (int i = tid; i < 2048; i += 256) wp[i] = W_proj[i];
    __syncthreads();
    int lane = tid & 63, wave = tid >> 6;
    int bid = blockIdx.x;
    int xcd = bid & 7, j = bid >> 3;          // j in [0,2000)
    int g = xcd * 4 + j / 500;
    int n = (j % 500) * 4 + wave;
    int w = g * NV + n;
    float s0 = scal[1], s1 = scal[2], s2 = scal[3], s3 = scal[4];
    const float4 ad = *(const float4*)(a_dst + (long)w * 4);
    const float* asrc_g = a_src + (long)g * NV * 4;
    const float* hg = h + (long)g * NV * 128;
    int start = rowptr[n], end = rowptr[n + 1];
    int half = lane >> 5, c = lane & 31;
    int hsel = c >> 3;                 // head of this lane's 4 channels
    float den0 = 0.f, den1 = 0.f, den2 = 0.f, den3 = 0.f;
    float4 msg = {0.f, 0.f, 0.f, 0.f};
    for (int base = start; base < end; base += 64) {
        int idx = base + lane;
        int se = 0; float e0 = 0.f, e1 = 0.f, e2 = 0.f, e3 = 0.f;
        if (idx < end) {
            se = csr_src[idx]; float ew = csr_ew[idx];
            float4 as = *(const float4*)(asrc_g + se * 4);
            float l0 = as.x + ad.x + ew * s0; l0 = l0 > 0.f ? l0 : 0.2f * l0; e0 = __expf(l0);
            float l1 = as.y + ad.y + ew * s1; l1 = l1 > 0.f ? l1 : 0.2f * l1; e1 = __expf(l1);
            float l2 = as.z + ad.z + ew * s2; l2 = l2 > 0.f ? l2 : 0.2f * l2; e2 = __expf(l2);
            float l3 = as.w + ad.w + ew * s3; l3 = l3 > 0.f ? l3 : 0.2f * l3; e3 = __expf(l3);
            den0 += e0; den1 += e1; den2 += e2; den3 += e3;
        }
        ssrc[wave][lane] = se;
        swt[wave][0][lane] = e0; swt[wave][1][lane] = e1;
        swt[wave][2][lane] = e2; swt[wave][3][lane] = e3;
        __builtin_amdgcn_wave_barrier();
        int cn = end - base; if (cn > 64) cn = 64;
        int npairs = (cn + 1) >> 1;
#pragma unroll 4
        for (int i = 0; i < npairs; i++) {
            int slot = 2 * i + half;
            int sse = ssrc[wave][slot];
            float wt = swt[wave][hsel][slot];
            const float4 hv = *(const float4*)(hg + (long)sse * 128 + c * 4);
            msg.x += wt * hv.x; msg.y += wt * hv.y; msg.z += wt * hv.z; msg.w += wt * hv.w;
        }
        __builtin_amdgcn_wave_barrier();
    }
#pragma unroll
    for (int d = 32; d; d >>= 1) {
        den0 += __shfl_xor(den0, d); den1 += __shfl_xor(den1, d);
        den2 += __shfl_xor(den2, d); den3 += __shfl_xor(den3, d);
    }
    float denh = (hsel == 0) ? den0 : (hsel == 1) ? den1 : (hsel == 2) ? den2 : den3;
    float inv = 1.f / (denh + 1e-16f);
    msg.x *= inv; msg.y *= inv; msg.z *= inv; msg.w *= inv;
    msg.x += __shfl_xor(msg.x, 32); msg.y += __shfl_xor(msg.y, 32);
    msg.z += __shfl_xor(msg.z, 32); msg.w += __shfl_xor(msg.w, 32);
    msg.x += __shfl_xor(msg.x, 8);  msg.y += __shfl_xor(msg.y, 8);
    msg.z += __shfl_xor(msg.z, 8);  msg.w += __shfl_xor(msg.w, 8);
    msg.x += __shfl_xor(msg.x, 16); msg.y += __shfl_xor(msg.y, 16);
    msg.z += __shfl_xor(msg.z, 16); msg.w += __shfl_xor(msg.w, 16);
    if (half == 0 && c < 8) {
        sout[wave][c * 4 + 0] = 0.25f * msg.x + gat_bias[c * 4 + 0];
        sout[wave][c * 4 + 1] = 0.25f * msg.y + gat_bias[c * 4 + 1];
        sout[wave][c * 4 + 2] = 0.25f * msg.z + gat_bias[c * 4 + 2];
        sout[wave][c * 4 + 3] = 0.25f * msg.w + gat_bias[c * 4 + 3];
    }
    __builtin_amdgcn_wave_barrier();
    float acc = b_proj[lane];
#pragma unroll
    for (int cc = 0; cc < 32; cc++) acc += sout[wave][cc] * wp[cc * 64 + lane];
    int b = g / TV, tt = g - b * TV;
    y[(((long)(b * NV + n)) * TV + tt) * 64 + lane] = acc;
}

// ---------------- K6: qkv (k,v all t; q only t=15) + attention + Wo + LN1 -> z1 ----------------
__global__ __launch_bounds__(256) void attn_kernel(const float* __restrict__ y, const float* __restrict__ Wqkv,
                                                   const float* __restrict__ bqkv, const float* __restrict__ Wo,
                                                   const float* __restrict__ bo, const float* __restrict__ ln1g,
                                                   const float* __restrict__ ln1b, float* __restrict__ z1) {
    __shared__ float yt[1024], kb[1024], vb[1024], wkv[8192], qv[64], pv[64], sc[64];
    int tid = threadIdx.x;
    int bn = blockIdx.x;
    const float* yb = y + (long)bn * 1024;
    for (int i = tid; i < 1024; i += 256) yt[i] = yb[i];
    for (int i = tid; i < 8192; i += 256) { int d = i >> 7, j = i & 127; wkv[i] = Wqkv[d * 192 + 64 + j]; }
    __syncthreads();
    for (int o = tid; o < 2048; o += 256) {
        int t = o >> 7, j = o & 127;
        float a = bqkv[64 + j];
        const float* yrow = &yt[t * 64];
#pragma unroll
        for (int d = 0; d < 64; d++) a += yrow[d] * wkv[d * 128 + j];
        if (j < 64) kb[t * 64 + j] = a; else vb[t * 64 + (j - 64)] = a;
    }
    if (tid < 64) {
        float a = bqkv[tid];
#pragma unroll
        for (int d = 0; d < 64; d++) a += yt[15 * 64 + d] * Wqkv[d * 192 + tid];
        qv[tid] = a;
    }
    __syncthreads();
    if (tid < 64) {
        int hh = tid >> 4, t = tid & 15;
        float s = 0.f;
#pragma unroll
        for (int dd = 0; dd < 16; dd++) s += qv[hh * 16 + dd] * kb[t * 64 + hh * 16 + dd];
        sc[tid] = s * 0.25f;
    }
    __syncthreads();
    if (tid < 64) {
        int hh = tid >> 4;
        float m = -INFINITY;
        for (int t = 0; t < 16; t++) m = fmaxf(m, sc[hh * 16 + t]);
        float den = 0.f;
        for (int t = 0; t < 16; t++) den += __expf(sc[hh * 16 + t] - m);
        pv[tid] = __expf(sc[tid] - m) / den;
    }
    __syncthreads();
    if (tid < 64) {
        int hh = tid >> 4;
        float ctx = 0.f;
#pragma unroll
        for (int t = 0; t < 16; t++) ctx += pv[hh * 16 + t] * vb[t * 64 + tid];
        sc[tid] = ctx;
    }
    __syncthreads();
    if (tid < 64) {
        float o = bo[tid];
#pragma unroll
        for (int j = 0; j < 64; j++) o += sc[j] * Wo[j * 64 + tid];
        float r = yt[15 * 64 + tid] + o;
        float sum = r, sq = r * r;
#pragma unroll
        for (int d = 32; d; d >>= 1) { sum += __shfl_xor(sum, d); sq += __shfl_xor(sq, d); }
        float mu = sum * (1.f / 64.f);
        float var = sq * (1.f / 64.f) - mu * mu;
        float zz = (r - mu) * rsqrtf(var + 1e-5f) * ln1g[tid] + ln1b[tid];
        z1[(long)bn * 64 + tid] = zz;
    }
}

// ---------------- K7-probe: empirically measure MFMA fragment layouts ----------------
// tbl[0..255]   = m_of[lane*4+reg]  (D-map row = A-side m)
// tbl[256..511] = n_of[lane*4+reg]  (D-map col = B-side n)
// tbl[512..543] = bslot_for_a[k']   (B slot index q*8+j paired with A slot label k')
__global__ void mfma_probe_kernel(int* __restrict__ tbl) {
    int lane = threadIdx.x;           // 64 threads
    int quad = lane >> 4, L = lane & 15;
    short one = f2bf(1.0f), Ls = f2bf((float)L);
    bf16x8 ones, lv, alab;
#pragma unroll
    for (int j = 0; j < 8; j++) { ones[j] = one; lv[j] = Ls; alab[j] = f2bf((float)(quad * 8 + j)); }
    f32x4 zero = {0.f, 0.f, 0.f, 0.f};
    // D = A(row-index) * B(ones): D[m][n] = 32*m  -> m_of
    f32x4 dm = __builtin_amdgcn_mfma_f32_16x16x32_bf16(lv, ones, zero, 0, 0, 0);
    // D = A(ones) * B(col-index): D[m][n] = 32*n  -> n_of
    f32x4 dn = __builtin_amdgcn_mfma_f32_16x16x32_bf16(ones, lv, zero, 0, 0, 0);
#pragma unroll
    for (int r = 0; r < 4; r++) {
        tbl[lane * 4 + r]       = (int)(dm[r] * (1.f / 32.f) + 0.5f);
        tbl[256 + lane * 4 + r] = (int)(dn[r] * (1.f / 32.f) + 0.5f);
    }
    // one-hot B per slot b: D = label of the A slot the HW pairs with B slot b
    for (int b = 0; b < 32; b++) {
        bf16x8 bh;
#pragma unroll
        for (int j = 0; j < 8; j++) bh[j] = (quad == (b >> 3) && j == (b & 7)) ? one : (short)0;
        f32x4 d = __builtin_amdgcn_mfma_f32_16x16x32_bf16(alab, bh, zero, 0, 0, 0);
        int a = (int)(d[0] + 0.5f);
        if (lane == 0) tbl[512 + a] = b;
    }
}

// ---------------- K7-pre: pack W1/W2 to bf16 using measured B-slot pairing ----------------
__global__ void pack_w1_kernel(const float* __restrict__ W1, short* __restrict__ pw1,
                               const int* __restrict__ tbl) {
    int i = blockIdx.x * 256 + threadIdx.x;   // over 64*2048
    if (i >= 64 * 2048) return;
    int k = i >> 11, n = i & 2047;
    int s = k >> 5, kp = k & 31;
    int b = tbl[512 + kp];                    // B slot paired with A-label kp
    int lane = (b >> 3) * 16 + (n & 15), jj = b & 7;
    int t = n >> 4;
    pw1[(((t * 2 + s) * 64 + lane) << 3) + jj] = f2bf(W1[i]);
}
__global__ void pack_w2_kernel(const float* __restrict__ W2, short* __restrict__ pw2,
                               const int* __restrict__ tbl) {
    int i = blockIdx.x * 256 + threadIdx.x;   // over 2048*64
    if (i >= 2048 * 64) return;
    int k = i >> 6, n = i & 63;
    int kt = k >> 5, kp = k & 31;
    int b = tbl[512 + kp];
    int lane = (b >> 3) * 16 + (n & 15), jj = b & 7;
    int nt = n >> 4;
    pw2[(((kt * 4 + nt) * 64 + lane) << 3) + jj] = f2bf(W2[i]);
}

// ---------------- K7: FF via bf16 MFMA (layout-table-driven) + residual + LN2 -> out ----------------
// 250 blocks x 4 waves. Block owns 16 rows; wave wv owns hidden channels [wv*512,(wv+1)*512).
__global__ __launch_bounds__(256) void ff_mfma_kernel(const float* __restrict__ z1,
        const short* __restrict__ pw1, const short* __restrict__ pw2,
        const float* __restrict__ b1, const float* __restrict__ b2,
        const float* __restrict__ ln2g, const float* __restrict__ ln2b,
        const int* __restrict__ tbl, float* __restrict__ out) {
    __shared__ __align__(16) short zb[16 * 72];        // z rows, bf16, padded
    __shared__ __align__(16) short hb[4][16 * 520];    // per-wave relu(hidden), bf16, padded
    __shared__ float part[4 * 16 * 64];                // per-wave GEMM2 partials
    int tid = threadIdx.x;
    int row0 = blockIdx.x * 16;
    for (int i = tid; i < 1024; i += 256)
        zb[(i >> 6) * 72 + (i & 63)] = f2bf(z1[(long)row0 * 64 + i]);
    __syncthreads();
    int lane = tid & 63, wv = tid >> 6;
    int quad = lane >> 4, m16 = lane & 15;
    int mo[4], no[4];
#pragma unroll
    for (int r = 0; r < 4; r++) { mo[r] = tbl[lane * 4 + r]; no[r] = tbl[256 + lane * 4 + r]; }
    // A staged with label map k = quad*8+j (pairing handled by packed B)
    bf16x8 a0 = *(const bf16x8*)&zb[m16 * 72 + quad * 8];        // k-block 0 (labels 0..31)
    bf16x8 a1 = *(const bf16x8*)&zb[m16 * 72 + 32 + quad * 8];   // k-block 1
    // GEMM1: hidden[16,512] = z @ W1[:, wv*512 : +512], +b1, relu -> hb (bf16)
    const short* pb1 = pw1 + (size_t)wv * 32 * 2 * 512;
    short* hbw = &hb[wv][0];
#pragma unroll 4
    for (int t = 0; t < 32; t++) {
        bf16x8 bA = *(const bf16x8*)(pb1 + ((t * 2 + 0) << 9) + (lane << 3));
        bf16x8 bB = *(const bf16x8*)(pb1 + ((t * 2 + 1) << 9) + (lane << 3));
        f32x4 acc = {0.f, 0.f, 0.f, 0.f};
        acc = __builtin_amdgcn_mfma_f32_16x16x32_bf16(a0, bA, acc, 0, 0, 0);
        acc = __builtin_amdgcn_mfma_f32_16x16x32_bf16(a1, bB, acc, 0, 0, 0);
#pragma unroll
        for (int r = 0; r < 4; r++) {
            float v = acc[r] + b1[wv * 512 + t * 16 + no[r]];
            v = v > 0.f ? v : 0.f;
            hbw[mo[r] * 520 + t * 16 + no[r]] = f2bf(v);   // measured D placement
        }
    }
    __syncthreads();
    // GEMM2: partial out[16,64] over k in wave's 512 channels
    f32x4 acc2[4] = {{0.f,0.f,0.f,0.f},{0.f,0.f,0.f,0.f},{0.f,0.f,0.f,0.f},{0.f,0.f,0.f,0.f}};
    const short* pb2 = pw2 + (size_t)wv * 16 * 4 * 512;
#pragma unroll 2
    for (int kt = 0; kt < 16; kt++) {
        bf16x8 af = *(const bf16x8*)&hbw[m16 * 520 + kt * 32 + quad * 8];
#pragma unroll
        for (int nt = 0; nt < 4; nt++) {
            bf16x8 bfr = *(const bf16x8*)(pb2 + ((kt * 4 + nt) << 9) + (lane << 3));
            acc2[nt] = __builtin_amdgcn_mfma_f32_16x16x32_bf16(af, bfr, acc2[nt], 0, 0, 0);
        }
    }
#pragma unroll
    for (int nt = 0; nt < 4; nt++)
#pragma unroll
        for (int r = 0; r < 4; r++)
            part[wv * 1024 + mo[r] * 64 + nt * 16 + no[r]] = acc2[nt][r];
    __syncthreads();
    // sum partials + residual + b2, then LN2 (lane = col, rows rq+{0,4,8,12})
    int col = tid & 63, rq = tid >> 6;
    float g = ln2g[col], bb = ln2b[col], bias2 = b2[col];
#pragma unroll
    for (int k2 = 0; k2 < 4; k2++) {
        int r = rq + k2 * 4;
        float val = part[r * 64 + col] + part[1024 + r * 64 + col]
                  + part[2048 + r * 64 + col] + part[3072 + r * 64 + col]
                  + z1[(long)(row0 + r) * 64 + col] + bias2;
        float sum = val, sq = val * val;
#pragma unroll
        for (int dlt = 32; dlt; dlt >>= 1) { sum += __shfl_xor(sum, dlt); sq += __shfl_xor(sq, dlt); }
        float mu = sum * (1.f / 64.f);
        float var = sq * (1.f / 64.f) - mu * mu;
        out[(long)(row0 + r) * 64 + col] = (val - mu) * rsqrtf(var + 1e-5f) * g + bb;
    }
}

extern "C" void kernel_launch(void* const* d_in, const int* in_sizes, int n_in,
                              void* d_out, int out_size, void* d_ws, size_t ws_size,
                              hipStream_t stream) {
    const float* x_seq      = (const float*)d_in[0];
    const int*   edge_index = (const int*)  d_in[1];
    const float* edge_weight= (const float*)d_in[2];
    const float* W_gat      = (const float*)d_in[3];
    const float* att_src    = (const float*)d_in[4];
    const float* att_dst    = (const float*)d_in[5];
    const float* W_edge     = (const float*)d_in[6];
    const float* att_edge   = (const float*)d_in[7];
    const float* gat_bias   = (const float*)d_in[8];
    const float* W_proj     = (const float*)d_in[9];
    const float* b_proj     = (const float*)d_in[10];
    const float* Wqkv       = (const float*)d_in[11];
    const float* bqkv       = (const float*)d_in[12];
    const float* Wo         = (const float*)d_in[13];
    const float* bo         = (const float*)d_in[14];
    const float* ln1g       = (const float*)d_in[15];
    const float* ln1b       = (const float*)d_in[16];
    const float* W1         = (const float*)d_in[17];
    const float* b1         = (const float*)d_in[18];
    const float* W2         = (const float*)d_in[19];
    const float* b2         = (const float*)d_in[20];
    const float* ln2g       = (const float*)d_in[21];
    const float* ln2b       = (const float*)d_in[22];
    float* outp = (float*)d_out;

    float* wsf = (float*)d_ws;
    float* h      = wsf + OFF_H;
    float* a_src  = wsf + OFF_ASRC;
    float* a_dst  = wsf + OFF_ADST;
    float* y      = wsf + OFF_Y;
    float* z1     = wsf + OFF_Z1;
    float* scal   = wsf + OFF_SCAL;
    int*   rowptr = (int*)(wsf + OFF_INTS);
    int*   cnt    = rowptr + 2001;
    int*   csr_src= cnt + 2000;
    float* csr_ew = wsf + OFF_CSREW;
    short* pw1    = (short*)(wsf + OFF_H);          // h dead after gat_agg
    short* pw2    = pw1 + 64 * 2048;
    int*   tbl    = (int*)(wsf + OFF_TBL);          // also inside dead h region (after pw1/pw2)

    prep_kernel<<<1, 256, 0, stream>>>(edge_weight, W_edge, att_edge, scal);
    hipMemsetAsync(cnt, 0, NV * sizeof(int), stream);
    hist_kernel<<<(ETV + 255) / 256, 256, 0, stream>>>(edge_index, cnt);
    scan_kernel<<<1, 256, 0, stream>>>(cnt, rowptr, cnt);
    scatter_kernel<<<(ETV + 255) / 256, 256, 0, stream>>>(edge_index, edge_weight, scal, cnt, csr_src, csr_ew);
    gat_h_kernel<<<GV * NV / 4, 256, 0, stream>>>(x_seq, W_gat, att_src, att_dst, h, a_src, a_dst);
    gat_agg_kernel<<<GV * NV / 4, 256, 0, stream>>>(h, a_src, a_dst, rowptr, csr_src, csr_ew, scal,
                                                    gat_bias, W_proj, b_proj, y);
    // h region dead now — probe MFMA layout, then pack FF weights per measured layout
    mfma_probe_kernel<<<1, 64, 0, stream>>>(tbl);
    pack_w1_kernel<<<(64 * 2048 + 255) / 256, 256, 0, stream>>>(W1, pw1, tbl);
    pack_w2_kernel<<<(2048 * 64 + 255) / 256, 256, 0, stream>>>(W2, pw2, tbl);
    attn_kernel<<<BV * NV, 256, 0, stream>>>(y, Wqkv, bqkv, Wo, bo, ln1g, ln1b, z1);
    ff_mfma_kernel<<<BV * NV / 16, 256, 0, stream>>>(z1, pw1, pw2, b1, b2, ln2g, ln2b, tbl, outp);
}

// Round 7
// 275.244 us; speedup vs baseline: 1.7836x; 1.1228x over previous
//
#include <hip/hip_runtime.h>
#include <math.h>

#define BV 2
#define TV 16
#define NV 2000
#define FIN 16
#define EV 32000
#define ETV 34000
#define GV 32
#define DD 64
#define FFV 2048

// workspace layout (float offsets)
#define OFF_H     0L          // h [32*2000*128] — dead after gat_agg; reused for packed bf16 W1/W2 + probe tbl
#define OFF_ASRC  8192000L
#define OFF_ADST  8448000L
#define OFF_Y     8704000L    // outg [2*2000*16*32] = 2048000 floats
#define OFF_WF    10752000L   // fused Wf [32*192], bfv [192]  (upper half of old y region)
#define OFF_Z1    12800000L
#define OFF_SCAL  13056000L   // [0]=ew_mean, [1..4]=s_h
#define OFF_INTS  13056016L   // rowptr[2001], cnt[2000], csr_src[34000]
#define OFF_CSREW 13094032L   // csr_ew[34000]
#define OFF_TBL   140000L     // int tbl[544] inside dead h region (after pw1/pw2)

typedef __attribute__((ext_vector_type(8))) short bf16x8;
typedef __attribute__((ext_vector_type(4))) float f32x4;

__device__ __forceinline__ short f2bf(float f) {
    union { float f; unsigned u; } v; v.f = f;
    unsigned r = v.u + 0x7FFFu + ((v.u >> 16) & 1u);   // round-to-nearest-even
    return (short)(r >> 16);
}

// ---------------- K-fuse: Wf = W_proj@Wqkv, bfv = b_proj@Wqkv + bqkv ----------------
__global__ void fuse_kernel(const float* __restrict__ Wproj, const float* __restrict__ bproj,
                            const float* __restrict__ Wqkv, const float* __restrict__ bqkv,
                            float* __restrict__ Wf, float* __restrict__ bfv) {
    int i = blockIdx.x * 256 + threadIdx.x;
    if (i < 32 * 192) {
        int c = i / 192, j = i - c * 192;
        float s = 0.f;
#pragma unroll
        for (int d = 0; d < 64; d++) s += Wproj[c * 64 + d] * Wqkv[d * 192 + j];
        Wf[i] = s;
    }
    if (i < 192) {
        float s = bqkv[i];
#pragma unroll
        for (int d = 0; d < 64; d++) s += bproj[d] * Wqkv[d * 192 + i];
        bfv[i] = s;
    }
}

// ---------------- K0: ew_mean + per-head edge-attention scalars ----------------
__global__ void prep_kernel(const float* __restrict__ ew, const float* __restrict__ W_edge,
                            const float* __restrict__ att_edge, float* __restrict__ scal) {
    __shared__ float red[256];
    int tid = threadIdx.x;
    float s = 0.f;
    for (int i = tid; i < EV; i += 256) s += ew[i];
    red[tid] = s; __syncthreads();
    for (int d = 128; d > 0; d >>= 1) { if (tid < d) red[tid] += red[tid + d]; __syncthreads(); }
    if (tid == 0) scal[0] = red[0] / (float)EV;
    __syncthreads();
    float p = (tid < 128) ? W_edge[tid] * att_edge[tid] : 0.f;
    red[tid] = p; __syncthreads();
    if (tid < 4) {
        float t = 0.f;
        for (int c = 0; c < 32; c++) t += red[tid * 32 + c];
        scal[1 + tid] = t;
    }
}

// ---------------- K1: in-degree histogram (incl. self loops) ----------------
__global__ void hist_kernel(const int* __restrict__ edge_index, int* __restrict__ deg) {
    int e = blockIdx.x * 256 + threadIdx.x;
    if (e >= ETV) return;
    int dst = (e < EV) ? edge_index[EV + e] : (e - EV);
    atomicAdd(&deg[dst], 1);
}

// ---------------- K2: exclusive scan -> rowptr, copy -> cnt ----------------
__global__ void scan_kernel(const int* __restrict__ deg, int* __restrict__ rowptr, int* __restrict__ cnt) {
    __shared__ int tot[256];
    int tid = threadIdx.x;
    int base = tid * 8;
    int local[8]; int s = 0;
    for (int i = 0; i < 8; i++) { int v = (base + i < NV) ? deg[base + i] : 0; local[i] = s; s += v; }
    tot[tid] = s; __syncthreads();
    for (int d = 1; d < 256; d <<= 1) {
        int v = (tid >= d) ? tot[tid - d] : 0;
        __syncthreads();
        tot[tid] += v;
        __syncthreads();
    }
    int ex = tot[tid] - s;
    for (int i = 0; i < 8; i++) {
        int idx = base + i;
        if (idx < NV) { int rp = ex + local[i]; rowptr[idx] = rp; cnt[idx] = rp; }
    }
    if (tid == 255) rowptr[NV] = tot[255];
}

// ---------------- K3: scatter edges into CSR ----------------
__global__ void scatter_kernel(const int* __restrict__ edge_index, const float* __restrict__ edge_weight,
                               const float* __restrict__ scal, int* __restrict__ cnt,
                               int* __restrict__ csr_src, float* __restrict__ csr_ew) {
    int e = blockIdx.x * 256 + threadIdx.x;
    if (e >= ETV) return;
    int src, dst; float w;
    if (e < EV) { src = edge_index[e]; dst = edge_index[EV + e]; w = edge_weight[e]; }
    else        { src = dst = e - EV; w = scal[0]; }
    int pos = atomicAdd(&cnt[dst], 1);
    csr_src[pos] = src; csr_ew[pos] = w;
}

// ---------------- K4: h = x@W_gat, a_src, a_dst (one wave per (g,n) row) ----------------
__global__ __launch_bounds__(256) void gat_h_kernel(const float* __restrict__ x, const float* __restrict__ W_gat,
                                                    const float* __restrict__ att_src, const float* __restrict__ att_dst,
                                                    float* __restrict__ h, float* __restrict__ a_src, float* __restrict__ a_dst) {
    __shared__ float wg[16 * 128];
    int tid = threadIdx.x;
    for (int i = tid; i < 2048; i += 256) wg[i] = W_gat[i];
    __syncthreads();
    int wave = tid >> 6, lane = tid & 63;
    int row = blockIdx.x * 4 + wave;           // row = g*N + n
    const float* xr = x + (long)row * 16;
    float xv[16];
#pragma unroll
    for (int f = 0; f < 16; f++) xv[f] = xr[f];
    float h0 = 0.f, h1 = 0.f;
#pragma unroll
    for (int f = 0; f < 16; f++) { h0 += xv[f] * wg[f * 128 + lane]; h1 += xv[f] * wg[f * 128 + lane + 64]; }
    h[(long)row * 128 + lane] = h0;
    h[(long)row * 128 + lane + 64] = h1;
    float p0 = h0 * att_src[lane], p1 = h1 * att_src[lane + 64];
    float q0 = h0 * att_dst[lane], q1 = h1 * att_dst[lane + 64];
#pragma unroll
    for (int d = 1; d < 32; d <<= 1) {
        p0 += __shfl_xor(p0, d); p1 += __shfl_xor(p1, d);
        q0 += __shfl_xor(q0, d); q1 += __shfl_xor(q1, d);
    }
    if (lane == 0)  { a_src[row * 4 + 0] = p0; a_src[row * 4 + 2] = p1; a_dst[row * 4 + 0] = q0; a_dst[row * 4 + 2] = q1; }
    if (lane == 32) { a_src[row * 4 + 1] = p0; a_src[row * 4 + 3] = p1; a_dst[row * 4 + 1] = q0; a_dst[row * 4 + 3] = q1; }
}

// ---------------- K5: segment softmax + aggregation + head mean -> outg (32 ch) ----------------
// 16000 blocks, XCD-swizzled; one wave per (g,n); NO block-level syncs (pure per-wave).
__global__ __launch_bounds__(256) void gat_agg_kernel(const float* __restrict__ h, const float* __restrict__ a_src,
                                                      const float* __restrict__ a_dst, const int* __restrict__ rowptr,
                                                      const int* __restrict__ csr_src, const float* __restrict__ csr_ew,
                                                      const float* __restrict__ scal, const float* __restrict__ gat_bias,
                                                      float* __restrict__ outg) {
    __shared__ int   ssrc[4][64];     // staged src indices per wave
    __shared__ float swt[4][4][65];   // staged exp-weights [wave][head][edge], padded
    int tid = threadIdx.x;
    int lane = tid & 63, wave = tid >> 6;
    int bid = blockIdx.x;
    int xcd = bid & 7, j = bid >> 3;          // j in [0,2000)
    int g = xcd * 4 + j / 500;
    int n = (j % 500) * 4 + wave;
    int w = g * NV + n;
    float s0 = scal[1], s1 = scal[2], s2 = scal[3], s3 = scal[4];
    const float4 ad = *(const float4*)(a_dst + (long)w * 4);
    const float* asrc_g = a_src + (long)g * NV * 4;
    const float* hg = h + (long)g * NV * 128;
    int start = rowptr[n], end = rowptr[n + 1];
    int half = lane >> 5, c = lane & 31;
    int hsel = c >> 3;                 // head of this lane's 4 channels
    float den0 = 0.f, den1 = 0.f, den2 = 0.f, den3 = 0.f;
    float4 msg = {0.f, 0.f, 0.f, 0.f};
    for (int base = start; base < end; base += 64) {
        int idx = base + lane;
        int se = 0; float e0 = 0.f, e1 = 0.f, e2 = 0.f, e3 = 0.f;
        if (idx < end) {
            se = csr_src[idx]; float ew = csr_ew[idx];
            float4 as = *(const float4*)(asrc_g + se * 4);
            float l0 = as.x + ad.x + ew * s0; l0 = l0 > 0.f ? l0 : 0.2f * l0; e0 = __expf(l0);
            float l1 = as.y + ad.y + ew * s1; l1 = l1 > 0.f ? l1 : 0.2f * l1; e1 = __expf(l1);
            float l2 = as.z + ad.z + ew * s2; l2 = l2 > 0.f ? l2 : 0.2f * l2; e2 = __expf(l2);
            float l3 = as.w + ad.w + ew * s3; l3 = l3 > 0.f ? l3 : 0.2f * l3; e3 = __expf(l3);
            den0 += e0; den1 += e1; den2 += e2; den3 += e3;
        }
        ssrc[wave][lane] = se;
        swt[wave][0][lane] = e0; swt[wave][1][lane] = e1;
        swt[wave][2][lane] = e2; swt[wave][3][lane] = e3;
        __builtin_amdgcn_wave_barrier();
        int cn = end - base; if (cn > 64) cn = 64;
        int npairs = (cn + 1) >> 1;
#pragma unroll 4
        for (int i = 0; i < npairs; i++) {
            int slot = 2 * i + half;
            int sse = ssrc[wave][slot];
            float wt = swt[wave][hsel][slot];
            const float4 hv = *(const float4*)(hg + (long)sse * 128 + c * 4);
            msg.x += wt * hv.x; msg.y += wt * hv.y; msg.z += wt * hv.z; msg.w += wt * hv.w;
        }
        __builtin_amdgcn_wave_barrier();
    }
#pragma unroll
    for (int d = 32; d; d >>= 1) {
        den0 += __shfl_xor(den0, d); den1 += __shfl_xor(den1, d);
        den2 += __shfl_xor(den2, d); den3 += __shfl_xor(den3, d);
    }
    float denh = (hsel == 0) ? den0 : (hsel == 1) ? den1 : (hsel == 2) ? den2 : den3;
    float inv = 1.f / (denh + 1e-16f);
    msg.x *= inv; msg.y *= inv; msg.z *= inv; msg.w *= inv;
    msg.x += __shfl_xor(msg.x, 32); msg.y += __shfl_xor(msg.y, 32);
    msg.z += __shfl_xor(msg.z, 32); msg.w += __shfl_xor(msg.w, 32);
    msg.x += __shfl_xor(msg.x, 8);  msg.y += __shfl_xor(msg.y, 8);
    msg.z += __shfl_xor(msg.z, 8);  msg.w += __shfl_xor(msg.w, 8);
    msg.x += __shfl_xor(msg.x, 16); msg.y += __shfl_xor(msg.y, 16);
    msg.z += __shfl_xor(msg.z, 16); msg.w += __shfl_xor(msg.w, 16);
    if (half == 0 && c < 8) {
        const float4 gb = *(const float4*)(gat_bias + c * 4);
        float4 o;
        o.x = 0.25f * msg.x + gb.x; o.y = 0.25f * msg.y + gb.y;
        o.z = 0.25f * msg.z + gb.z; o.w = 0.25f * msg.w + gb.w;
        int b = g / TV, tt = g - b * TV;
        *(float4*)(outg + (((long)(b * NV + n)) * TV + tt) * 32 + c * 4) = o;
    }
}

// ---------------- K6: fused qkv (K=32) + attention + Wo + LN1 -> z1 ----------------
__global__ __launch_bounds__(256) void attn_kernel(const float* __restrict__ og, const float* __restrict__ Wf,
                                                   const float* __restrict__ bfv, const float* __restrict__ Wproj,
                                                   const float* __restrict__ bproj, const float* __restrict__ Wo,
                                                   const float* __restrict__ bo, const float* __restrict__ ln1g,
                                                   const float* __restrict__ ln1b, float* __restrict__ z1) {
    __shared__ float ot[512], wkvf[4096], kb[1024], vb[1024], qv[64], pv[64], sc[64], yv[64];
    int tid = threadIdx.x;
    int bn = blockIdx.x;
    const float* ob = og + (long)bn * 512;
    for (int i = tid; i < 512; i += 256) ot[i] = ob[i];
    for (int i = tid; i < 4096; i += 256) { int d = i >> 7, j = i & 127; wkvf[i] = Wf[d * 192 + 64 + j]; }
    __syncthreads();
    // k,v for all t (K=32 fused weights; per-thread weight column in registers)
    {
        int j = tid & 127, tb = tid >> 7;
        float wcol[32];
#pragma unroll
        for (int d = 0; d < 32; d++) wcol[d] = wkvf[d * 128 + j];
        float bias = bfv[64 + j];
#pragma unroll
        for (int k = 0; k < 8; k++) {
            int t = 2 * k + tb;
            const float* orow = &ot[t * 32];
            float a = bias;
#pragma unroll
            for (int d = 0; d < 32; d++) a += orow[d] * wcol[d];
            if (j < 64) kb[t * 64 + j] = a; else vb[t * 64 + (j - 64)] = a;
        }
    }
    // q and residual y for t = 15 (wave 0)
    if (tid < 64) {
        float a = bfv[tid];
        float yr = bproj[tid];
#pragma unroll
        for (int d = 0; d < 32; d++) {
            float od = ot[15 * 32 + d];
            a  += od * Wf[d * 192 + tid];
            yr += od * Wproj[d * 64 + tid];
        }
        qv[tid] = a; yv[tid] = yr;
    }
    __syncthreads();
    if (tid < 64) {
        int hh = tid >> 4, t = tid & 15;
        float s = 0.f;
#pragma unroll
        for (int dd = 0; dd < 16; dd++) s += qv[hh * 16 + dd] * kb[t * 64 + hh * 16 + dd];
        sc[tid] = s * 0.25f;
    }
    __syncthreads();
    if (tid < 64) {
        int hh = tid >> 4;
        float m = -INFINITY;
        for (int t = 0; t < 16; t++) m = fmaxf(m, sc[hh * 16 + t]);
        float den = 0.f;
        for (int t = 0; t < 16; t++) den += __expf(sc[hh * 16 + t] - m);
        pv[tid] = __expf(sc[tid] - m) / den;
    }
    __syncthreads();
    if (tid < 64) {
        int hh = tid >> 4;
        float ctx = 0.f;
#pragma unroll
        for (int t = 0; t < 16; t++) ctx += pv[hh * 16 + t] * vb[t * 64 + tid];
        sc[tid] = ctx;
    }
    __syncthreads();
    if (tid < 64) {
        float o = bo[tid];
#pragma unroll
        for (int j = 0; j < 64; j++) o += sc[j] * Wo[j * 64 + tid];
        float r = yv[tid] + o;
        float sum = r, sq = r * r;
#pragma unroll
        for (int d = 32; d; d >>= 1) { sum += __shfl_xor(sum, d); sq += __shfl_xor(sq, d); }
        float mu = sum * (1.f / 64.f);
        float var = sq * (1.f / 64.f) - mu * mu;
        float zz = (r - mu) * rsqrtf(var + 1e-5f) * ln1g[tid] + ln1b[tid];
        z1[(long)bn * 64 + tid] = zz;
    }
}

// ---------------- K7-probe: empirically measure MFMA fragment layouts ----------------
__global__ void mfma_probe_kernel(int* __restrict__ tbl) {
    int lane = threadIdx.x;           // 64 threads
    int quad = lane >> 4, L = lane & 15;
    short one = f2bf(1.0f), Ls = f2bf((float)L);
    bf16x8 ones, lv, alab;
#pragma unroll
    for (int j = 0; j < 8; j++) { ones[j] = one; lv[j] = Ls; alab[j] = f2bf((float)(quad * 8 + j)); }
    f32x4 zero = {0.f, 0.f, 0.f, 0.f};
    f32x4 dm = __builtin_amdgcn_mfma_f32_16x16x32_bf16(lv, ones, zero, 0, 0, 0);
    f32x4 dn = __builtin_amdgcn_mfma_f32_16x16x32_bf16(ones, lv, zero, 0, 0, 0);
#pragma unroll
    for (int r = 0; r < 4; r++) {
        tbl[lane * 4 + r]       = (int)(dm[r] * (1.f / 32.f) + 0.5f);
        tbl[256 + lane * 4 + r] = (int)(dn[r] * (1.f / 32.f) + 0.5f);
    }
    for (int b = 0; b < 32; b++) {
        bf16x8 bh;
#pragma unroll
        for (int j = 0; j < 8; j++) bh[j] = (quad == (b >> 3) && j == (b & 7)) ? one : (short)0;
        f32x4 d = __builtin_amdgcn_mfma_f32_16x16x32_bf16(alab, bh, zero, 0, 0, 0);
        int a = (int)(d[0] + 0.5f);
        if (lane == 0) tbl[512 + a] = b;
    }
}

// ---------------- K7-pre: pack W1/W2 to bf16 using measured B-slot pairing ----------------
__global__ void pack_w1_kernel(const float* __restrict__ W1, short* __restrict__ pw1,
                               const int* __restrict__ tbl) {
    int i = blockIdx.x * 256 + threadIdx.x;   // over 64*2048
    if (i >= 64 * 2048) return;
    int k = i >> 11, n = i & 2047;
    int s = k >> 5, kp = k & 31;
    int b = tbl[512 + kp];
    int lane = (b >> 3) * 16 + (n & 15), jj = b & 7;
    int t = n >> 4;
    pw1[(((t * 2 + s) * 64 + lane) << 3) + jj] = f2bf(W1[i]);
}
__global__ void pack_w2_kernel(const float* __restrict__ W2, short* __restrict__ pw2,
                               const int* __restrict__ tbl) {
    int i = blockIdx.x * 256 + threadIdx.x;   // over 2048*64
    if (i >= 2048 * 64) return;
    int k = i >> 6, n = i & 63;
    int kt = k >> 5, kp = k & 31;
    int b = tbl[512 + kp];
    int lane = (b >> 3) * 16 + (n & 15), jj = b & 7;
    int nt = n >> 4;
    pw2[(((kt * 4 + nt) * 64 + lane) << 3) + jj] = f2bf(W2[i]);
}

// ---------------- K7: FF via bf16 MFMA (layout-table-driven) + residual + LN2 -> out ----------------
__global__ __launch_bounds__(256) void ff_mfma_kernel(const float* __restrict__ z1,
        const short* __restrict__ pw1, const short* __restrict__ pw2,
        const float* __restrict__ b1, const float* __restrict__ b2,
        const float* __restrict__ ln2g, const float* __restrict__ ln2b,
        const int* __restrict__ tbl, float* __restrict__ out) {
    __shared__ __align__(16) short zb[16 * 72];
    __shared__ __align__(16) short hb[4][16 * 520];
    __shared__ float part[4 * 16 * 64];
    int tid = threadIdx.x;
    int row0 = blockIdx.x * 16;
    for (int i = tid; i < 1024; i += 256)
        zb[(i >> 6) * 72 + (i & 63)] = f2bf(z1[(long)row0 * 64 + i]);
    __syncthreads();
    int lane = tid & 63, wv = tid >> 6;
    int quad = lane >> 4, m16 = lane & 15;
    int mo[4], no[4];
#pragma unroll
    for (int r = 0; r < 4; r++) { mo[r] = tbl[lane * 4 + r]; no[r] = tbl[256 + lane * 4 + r]; }
    bf16x8 a0 = *(const bf16x8*)&zb[m16 * 72 + quad * 8];
    bf16x8 a1 = *(const bf16x8*)&zb[m16 * 72 + 32 + quad * 8];
    const short* pb1 = pw1 + (size_t)wv * 32 * 2 * 512;
    short* hbw = &hb[wv][0];
#pragma unroll 4
    for (int t = 0; t < 32; t++) {
        bf16x8 bA = *(const bf16x8*)(pb1 + ((t * 2 + 0) << 9) + (lane << 3));
        bf16x8 bB = *(const bf16x8*)(pb1 + ((t * 2 + 1) << 9) + (lane << 3));
        f32x4 acc = {0.f, 0.f, 0.f, 0.f};
        acc = __builtin_amdgcn_mfma_f32_16x16x32_bf16(a0, bA, acc, 0, 0, 0);
        acc = __builtin_amdgcn_mfma_f32_16x16x32_bf16(a1, bB, acc, 0, 0, 0);
#pragma unroll
        for (int r = 0; r < 4; r++) {
            float v = acc[r] + b1[wv * 512 + t * 16 + no[r]];
            v = v > 0.f ? v : 0.f;
            hbw[mo[r] * 520 + t * 16 + no[r]] = f2bf(v);
        }
    }
    __syncthreads();
    f32x4 acc2[4] = {{0.f,0.f,0.f,0.f},{0.f,0.f,0.f,0.f},{0.f,0.f,0.f,0.f},{0.f,0.f,0.f,0.f}};
    const short* pb2 = pw2 + (size_t)wv * 16 * 4 * 512;
#pragma unroll 2
    for (int kt = 0; kt < 16; kt++) {
        bf16x8 af = *(const bf16x8*)&hbw[m16 * 520 + kt * 32 + quad * 8];
#pragma unroll
        for (int nt = 0; nt < 4; nt++) {
            bf16x8 bfr = *(const bf16x8*)(pb2 + ((kt * 4 + nt) << 9) + (lane << 3));
            acc2[nt] = __builtin_amdgcn_mfma_f32_16x16x32_bf16(af, bfr, acc2[nt], 0, 0, 0);
        }
    }
#pragma unroll
    for (int nt = 0; nt < 4; nt++)
#pragma unroll
        for (int r = 0; r < 4; r++)
            part[wv * 1024 + mo[r] * 64 + nt * 16 + no[r]] = acc2[nt][r];
    __syncthreads();
    int col = tid & 63, rq = tid >> 6;
    float g = ln2g[col], bb = ln2b[col], bias2 = b2[col];
#pragma unroll
    for (int k2 = 0; k2 < 4; k2++) {
        int r = rq + k2 * 4;
        float val = part[r * 64 + col] + part[1024 + r * 64 + col]
                  + part[2048 + r * 64 + col] + part[3072 + r * 64 + col]
                  + z1[(long)(row0 + r) * 64 + col] + bias2;
        float sum = val, sq = val * val;
#pragma unroll
        for (int dlt = 32; dlt; dlt >>= 1) { sum += __shfl_xor(sum, dlt); sq += __shfl_xor(sq, dlt); }
        float mu = sum * (1.f / 64.f);
        float var = sq * (1.f / 64.f) - mu * mu;
        out[(long)(row0 + r) * 64 + col] = (val - mu) * rsqrtf(var + 1e-5f) * g + bb;
    }
}

extern "C" void kernel_launch(void* const* d_in, const int* in_sizes, int n_in,
                              void* d_out, int out_size, void* d_ws, size_t ws_size,
                              hipStream_t stream) {
    const float* x_seq      = (const float*)d_in[0];
    const int*   edge_index = (const int*)  d_in[1];
    const float* edge_weight= (const float*)d_in[2];
    const float* W_gat      = (const float*)d_in[3];
    const float* att_src    = (const float*)d_in[4];
    const float* att_dst    = (const float*)d_in[5];
    const float* W_edge     = (const float*)d_in[6];
    const float* att_edge   = (const float*)d_in[7];
    const float* gat_bias   = (const float*)d_in[8];
    const float* W_proj     = (const float*)d_in[9];
    const float* b_proj     = (const float*)d_in[10];
    const float* Wqkv       = (const float*)d_in[11];
    const float* bqkv       = (const float*)d_in[12];
    const float* Wo         = (const float*)d_in[13];
    const float* bo         = (const float*)d_in[14];
    const float* ln1g       = (const float*)d_in[15];
    const float* ln1b       = (const float*)d_in[16];
    const float* W1         = (const float*)d_in[17];
    const float* b1         = (const float*)d_in[18];
    const float* W2         = (const float*)d_in[19];
    const float* b2         = (const float*)d_in[20];
    const float* ln2g       = (const float*)d_in[21];
    const float* ln2b       = (const float*)d_in[22];
    float* outp = (float*)d_out;

    float* wsf = (float*)d_ws;
    float* h      = wsf + OFF_H;
    float* a_src  = wsf + OFF_ASRC;
    float* a_dst  = wsf + OFF_ADST;
    float* outg   = wsf + OFF_Y;
    float* Wfused = wsf + OFF_WF;
    float* bfv    = Wfused + 32 * 192;
    float* z1     = wsf + OFF_Z1;
    float* scal   = wsf + OFF_SCAL;
    int*   rowptr = (int*)(wsf + OFF_INTS);
    int*   cnt    = rowptr + 2001;
    int*   csr_src= cnt + 2000;
    float* csr_ew = wsf + OFF_CSREW;
    short* pw1    = (short*)(wsf + OFF_H);          // h dead after gat_agg
    short* pw2    = pw1 + 64 * 2048;
    int*   tbl    = (int*)(wsf + OFF_TBL);

    fuse_kernel<<<24, 256, 0, stream>>>(W_proj, b_proj, Wqkv, bqkv, Wfused, bfv);
    prep_kernel<<<1, 256, 0, stream>>>(edge_weight, W_edge, att_edge, scal);
    hipMemsetAsync(cnt, 0, NV * sizeof(int), stream);
    hist_kernel<<<(ETV + 255) / 256, 256, 0, stream>>>(edge_index, cnt);
    scan_kernel<<<1, 256, 0, stream>>>(cnt, rowptr, cnt);
    scatter_kernel<<<(ETV + 255) / 256, 256, 0, stream>>>(edge_index, edge_weight, scal, cnt, csr_src, csr_ew);
    gat_h_kernel<<<GV * NV / 4, 256, 0, stream>>>(x_seq, W_gat, att_src, att_dst, h, a_src, a_dst);
    gat_agg_kernel<<<GV * NV / 4, 256, 0, stream>>>(h, a_src, a_dst, rowptr, csr_src, csr_ew, scal,
                                                    gat_bias, outg);
    mfma_probe_kernel<<<1, 64, 0, stream>>>(tbl);
    pack_w1_kernel<<<(64 * 2048 + 255) / 256, 256, 0, stream>>>(W1, pw1, tbl);
    pack_w2_kernel<<<(2048 * 64 + 255) / 256, 256, 0, stream>>>(W2, pw2, tbl);
    attn_kernel<<<BV * NV, 256, 0, stream>>>(outg, Wfused, bfv, W_proj, b_proj, Wo, bo, ln1g, ln1b, z1);
    ff_mfma_kernel<<<BV * NV / 16, 256, 0, stream>>>(z1, pw1, pw2, b1, b2, ln2g, ln2b, tbl, outp);
}

// Round 8
// 244.538 us; speedup vs baseline: 2.0075x; 1.1256x over previous
//
#include <hip/hip_runtime.h>
#include <math.h>

#define BV 2
#define TV 16
#define NV 2000
#define FIN 16
#define EV 32000
#define ETV 34000
#define GV 32
#define DD 64
#define FFV 2048

// workspace layout (float offsets)
#define OFF_H     0L          // h [32*2000*128] — dead after gat_agg; reused for packed bf16 W1/W2 + probe tbl
#define OFF_ASRC  8192000L
#define OFF_ADST  8448000L
#define OFF_Y     8704000L    // outg [2*2000*16*32] = 2048000 floats
#define OFF_WF    10752000L   // fused Wf [32*192], bfv [192]
#define OFF_Z1    12800000L
#define OFF_SCAL  13056000L   // [0]=ew_mean, [1..4]=s_h
#define OFF_INTS  13056016L   // rowptr[2001], cnt[2000], csr_src[34000]
#define OFF_CSREW 13094032L   // csr_ew[34000]
#define OFF_TBL   140000L     // int tbl[544] inside dead h region (after pw1/pw2)

typedef __attribute__((ext_vector_type(8))) short bf16x8;
typedef __attribute__((ext_vector_type(4))) float f32x4;

__device__ __forceinline__ short f2bf(float f) {
    union { float f; unsigned u; } v; v.f = f;
    unsigned r = v.u + 0x7FFFu + ((v.u >> 16) & 1u);   // round-to-nearest-even
    return (short)(r >> 16);
}

// ---------------- K-fuse: Wf = W_proj@Wqkv, bfv = b_proj@Wqkv + bqkv ----------------
__global__ void fuse_kernel(const float* __restrict__ Wproj, const float* __restrict__ bproj,
                            const float* __restrict__ Wqkv, const float* __restrict__ bqkv,
                            float* __restrict__ Wf, float* __restrict__ bfv) {
    int i = blockIdx.x * 256 + threadIdx.x;
    if (i < 32 * 192) {
        int c = i / 192, j = i - c * 192;
        float s = 0.f;
#pragma unroll
        for (int d = 0; d < 64; d++) s += Wproj[c * 64 + d] * Wqkv[d * 192 + j];
        Wf[i] = s;
    }
    if (i < 192) {
        float s = bqkv[i];
#pragma unroll
        for (int d = 0; d < 64; d++) s += bproj[d] * Wqkv[d * 192 + i];
        bfv[i] = s;
    }
}

// ---------------- K0a: parallel edge-weight sum (atomic) ----------------
__global__ void ew_sum_kernel(const float* __restrict__ ew, float* __restrict__ scal) {
    int i = blockIdx.x * 256 + threadIdx.x;
    float v = (i < EV) ? ew[i] : 0.f;
#pragma unroll
    for (int d = 32; d; d >>= 1) v += __shfl_xor(v, d);
    if ((threadIdx.x & 63) == 0) atomicAdd(&scal[0], v);
}

// ---------------- K0b: finalize ew_mean + per-head edge-attention scalars ----------------
__global__ void prep2_kernel(const float* __restrict__ W_edge, const float* __restrict__ att_edge,
                             float* __restrict__ scal) {
    __shared__ float red[128];
    int tid = threadIdx.x;   // 128 threads
    red[tid] = W_edge[tid] * att_edge[tid];
    __syncthreads();
    if (tid == 0) scal[0] = scal[0] * (1.f / (float)EV);
    if (tid < 4) {
        float t = 0.f;
#pragma unroll
        for (int c = 0; c < 32; c++) t += red[tid * 32 + c];
        scal[1 + tid] = t;
    }
}

// ---------------- K1: in-degree histogram (incl. self loops) ----------------
__global__ void hist_kernel(const int* __restrict__ edge_index, int* __restrict__ deg) {
    int e = blockIdx.x * 256 + threadIdx.x;
    if (e >= ETV) return;
    int dst = (e < EV) ? edge_index[EV + e] : (e - EV);
    atomicAdd(&deg[dst], 1);
}

// ---------------- K2: exclusive scan -> rowptr, copy -> cnt ----------------
__global__ void scan_kernel(const int* __restrict__ deg, int* __restrict__ rowptr, int* __restrict__ cnt) {
    __shared__ int tot[256];
    int tid = threadIdx.x;
    int base = tid * 8;
    int local[8]; int s = 0;
    for (int i = 0; i < 8; i++) { int v = (base + i < NV) ? deg[base + i] : 0; local[i] = s; s += v; }
    tot[tid] = s; __syncthreads();
    for (int d = 1; d < 256; d <<= 1) {
        int v = (tid >= d) ? tot[tid - d] : 0;
        __syncthreads();
        tot[tid] += v;
        __syncthreads();
    }
    int ex = tot[tid] - s;
    for (int i = 0; i < 8; i++) {
        int idx = base + i;
        if (idx < NV) { int rp = ex + local[i]; rowptr[idx] = rp; cnt[idx] = rp; }
    }
    if (tid == 255) rowptr[NV] = tot[255];
}

// ---------------- K3: scatter edges into CSR ----------------
__global__ void scatter_kernel(const int* __restrict__ edge_index, const float* __restrict__ edge_weight,
                               const float* __restrict__ scal, int* __restrict__ cnt,
                               int* __restrict__ csr_src, float* __restrict__ csr_ew) {
    int e = blockIdx.x * 256 + threadIdx.x;
    if (e >= ETV) return;
    int src, dst; float w;
    if (e < EV) { src = edge_index[e]; dst = edge_index[EV + e]; w = edge_weight[e]; }
    else        { src = dst = e - EV; w = scal[0]; }
    int pos = atomicAdd(&cnt[dst], 1);
    csr_src[pos] = src; csr_ew[pos] = w;
}

// ---------------- K4: h = x@W_gat, a_src, a_dst (4 rows per wave, weights in regs) ----------------
__global__ __launch_bounds__(256) void gat_h_kernel(const float* __restrict__ x, const float* __restrict__ W_gat,
                                                    const float* __restrict__ att_src, const float* __restrict__ att_dst,
                                                    float* __restrict__ h, float* __restrict__ a_src, float* __restrict__ a_dst) {
    int tid = threadIdx.x;
    int lane = tid & 63, wave = tid >> 6;
    int row0 = blockIdx.x * 16 + wave * 4;
    float w0[16], w1[16];
#pragma unroll
    for (int f = 0; f < 16; f++) { w0[f] = W_gat[f * 128 + lane]; w1[f] = W_gat[f * 128 + 64 + lane]; }
    float as0 = att_src[lane], as1 = att_src[lane + 64];
    float ad0 = att_dst[lane], ad1 = att_dst[lane + 64];
#pragma unroll
    for (int r = 0; r < 4; r++) {
        int row = row0 + r;
        const float4* xr = (const float4*)(x + (long)row * 16);
        float4 xa = xr[0], xb = xr[1], xc = xr[2], xd = xr[3];
        float xv[16] = {xa.x, xa.y, xa.z, xa.w, xb.x, xb.y, xb.z, xb.w,
                        xc.x, xc.y, xc.z, xc.w, xd.x, xd.y, xd.z, xd.w};
        float h0 = 0.f, h1 = 0.f;
#pragma unroll
        for (int f = 0; f < 16; f++) { h0 += xv[f] * w0[f]; h1 += xv[f] * w1[f]; }
        h[(long)row * 128 + lane] = h0;
        h[(long)row * 128 + 64 + lane] = h1;
        float p0 = h0 * as0, p1 = h1 * as1;
        float q0 = h0 * ad0, q1 = h1 * ad1;
#pragma unroll
        for (int d = 1; d < 32; d <<= 1) {
            p0 += __shfl_xor(p0, d); p1 += __shfl_xor(p1, d);
            q0 += __shfl_xor(q0, d); q1 += __shfl_xor(q1, d);
        }
        if (lane == 0)  { a_src[row * 4 + 0] = p0; a_src[row * 4 + 2] = p1; a_dst[row * 4 + 0] = q0; a_dst[row * 4 + 2] = q1; }
        if (lane == 32) { a_src[row * 4 + 1] = p0; a_src[row * 4 + 3] = p1; a_dst[row * 4 + 1] = q0; a_dst[row * 4 + 3] = q1; }
    }
}

// ---------------- K5: segment softmax + aggregation + head mean -> outg (32 ch) ----------------
__global__ __launch_bounds__(256) void gat_agg_kernel(const float* __restrict__ h, const float* __restrict__ a_src,
                                                      const float* __restrict__ a_dst, const int* __restrict__ rowptr,
                                                      const int* __restrict__ csr_src, const float* __restrict__ csr_ew,
                                                      const float* __restrict__ scal, const float* __restrict__ gat_bias,
                                                      float* __restrict__ outg) {
    __shared__ int   ssrc[4][64];
    __shared__ float swt[4][4][65];
    int tid = threadIdx.x;
    int lane = tid & 63, wave = tid >> 6;
    int bid = blockIdx.x;
    int xcd = bid & 7, j = bid >> 3;
    int g = xcd * 4 + j / 500;
    int n = (j % 500) * 4 + wave;
    int w = g * NV + n;
    float s0 = scal[1], s1 = scal[2], s2 = scal[3], s3 = scal[4];
    const float4 ad = *(const float4*)(a_dst + (long)w * 4);
    const float* asrc_g = a_src + (long)g * NV * 4;
    const float* hg = h + (long)g * NV * 128;
    int start = rowptr[n], end = rowptr[n + 1];
    int half = lane >> 5, c = lane & 31;
    int hsel = c >> 3;
    float den0 = 0.f, den1 = 0.f, den2 = 0.f, den3 = 0.f;
    float4 msg = {0.f, 0.f, 0.f, 0.f};
    for (int base = start; base < end; base += 64) {
        int idx = base + lane;
        int se = 0; float e0 = 0.f, e1 = 0.f, e2 = 0.f, e3 = 0.f;
        if (idx < end) {
            se = csr_src[idx]; float ew = csr_ew[idx];
            float4 as = *(const float4*)(asrc_g + se * 4);
            float l0 = as.x + ad.x + ew * s0; l0 = l0 > 0.f ? l0 : 0.2f * l0; e0 = __expf(l0);
            float l1 = as.y + ad.y + ew * s1; l1 = l1 > 0.f ? l1 : 0.2f * l1; e1 = __expf(l1);
            float l2 = as.z + ad.z + ew * s2; l2 = l2 > 0.f ? l2 : 0.2f * l2; e2 = __expf(l2);
            float l3 = as.w + ad.w + ew * s3; l3 = l3 > 0.f ? l3 : 0.2f * l3; e3 = __expf(l3);
            den0 += e0; den1 += e1; den2 += e2; den3 += e3;
        }
        ssrc[wave][lane] = se;
        swt[wave][0][lane] = e0; swt[wave][1][lane] = e1;
        swt[wave][2][lane] = e2; swt[wave][3][lane] = e3;
        __builtin_amdgcn_wave_barrier();
        int cn = end - base; if (cn > 64) cn = 64;
        int npairs = (cn + 1) >> 1;
#pragma unroll 4
        for (int i = 0; i < npairs; i++) {
            int slot = 2 * i + half;
            int sse = ssrc[wave][slot];
            float wt = swt[wave][hsel][slot];
            const float4 hv = *(const float4*)(hg + (long)sse * 128 + c * 4);
            msg.x += wt * hv.x; msg.y += wt * hv.y; msg.z += wt * hv.z; msg.w += wt * hv.w;
        }
        __builtin_amdgcn_wave_barrier();
    }
#pragma unroll
    for (int d = 32; d; d >>= 1) {
        den0 += __shfl_xor(den0, d); den1 += __shfl_xor(den1, d);
        den2 += __shfl_xor(den2, d); den3 += __shfl_xor(den3, d);
    }
    float denh = (hsel == 0) ? den0 : (hsel == 1) ? den1 : (hsel == 2) ? den2 : den3;
    float inv = 1.f / (denh + 1e-16f);
    msg.x *= inv; msg.y *= inv; msg.z *= inv; msg.w *= inv;
    msg.x += __shfl_xor(msg.x, 32); msg.y += __shfl_xor(msg.y, 32);
    msg.z += __shfl_xor(msg.z, 32); msg.w += __shfl_xor(msg.w, 32);
    msg.x += __shfl_xor(msg.x, 8);  msg.y += __shfl_xor(msg.y, 8);
    msg.z += __shfl_xor(msg.z, 8);  msg.w += __shfl_xor(msg.w, 8);
    msg.x += __shfl_xor(msg.x, 16); msg.y += __shfl_xor(msg.y, 16);
    msg.z += __shfl_xor(msg.z, 16); msg.w += __shfl_xor(msg.w, 16);
    if (half == 0 && c < 8) {
        const float4 gb = *(const float4*)(gat_bias + c * 4);
        float4 o;
        o.x = 0.25f * msg.x + gb.x; o.y = 0.25f * msg.y + gb.y;
        o.z = 0.25f * msg.z + gb.z; o.w = 0.25f * msg.w + gb.w;
        int b = g / TV, tt = g - b * TV;
        *(float4*)(outg + (((long)(b * NV + n)) * TV + tt) * 32 + c * 4) = o;
    }
}

// ---------------- K6: fused qkv (K=32) + attention + Wo + LN1 -> z1 ----------------
__global__ __launch_bounds__(256) void attn_kernel(const float* __restrict__ og, const float* __restrict__ Wf,
                                                   const float* __restrict__ bfv, const float* __restrict__ Wproj,
                                                   const float* __restrict__ bproj, const float* __restrict__ Wo,
                                                   const float* __restrict__ bo, const float* __restrict__ ln1g,
                                                   const float* __restrict__ ln1b, float* __restrict__ z1) {
    __shared__ float ot[512], wkvf[4096], kb[1024], vb[1024], qv[64], pv[64], sc[64], yv[64];
    int tid = threadIdx.x;
    int bn = blockIdx.x;
    const float* ob = og + (long)bn * 512;
    for (int i = tid; i < 512; i += 256) ot[i] = ob[i];
    for (int i = tid; i < 4096; i += 256) { int d = i >> 7, j = i & 127; wkvf[i] = Wf[d * 192 + 64 + j]; }
    __syncthreads();
    {
        int j = tid & 127, tb = tid >> 7;
        float wcol[32];
#pragma unroll
        for (int d = 0; d < 32; d++) wcol[d] = wkvf[d * 128 + j];
        float bias = bfv[64 + j];
#pragma unroll
        for (int k = 0; k < 8; k++) {
            int t = 2 * k + tb;
            const float* orow = &ot[t * 32];
            float a = bias;
#pragma unroll
            for (int d = 0; d < 32; d++) a += orow[d] * wcol[d];
            if (j < 64) kb[t * 64 + j] = a; else vb[t * 64 + (j - 64)] = a;
        }
    }
    if (tid < 64) {
        float a = bfv[tid];
        float yr = bproj[tid];
#pragma unroll
        for (int d = 0; d < 32; d++) {
            float od = ot[15 * 32 + d];
            a  += od * Wf[d * 192 + tid];
            yr += od * Wproj[d * 64 + tid];
        }
        qv[tid] = a; yv[tid] = yr;
    }
    __syncthreads();
    if (tid < 64) {
        int hh = tid >> 4, t = tid & 15;
        float s = 0.f;
#pragma unroll
        for (int dd = 0; dd < 16; dd++) s += qv[hh * 16 + dd] * kb[t * 64 + hh * 16 + dd];
        sc[tid] = s * 0.25f;
    }
    __syncthreads();
    if (tid < 64) {
        int hh = tid >> 4;
        float m = -INFINITY;
        for (int t = 0; t < 16; t++) m = fmaxf(m, sc[hh * 16 + t]);
        float den = 0.f;
        for (int t = 0; t < 16; t++) den += __expf(sc[hh * 16 + t] - m);
        pv[tid] = __expf(sc[tid] - m) / den;
    }
    __syncthreads();
    if (tid < 64) {
        int hh = tid >> 4;
        float ctx = 0.f;
#pragma unroll
        for (int t = 0; t < 16; t++) ctx += pv[hh * 16 + t] * vb[t * 64 + tid];
        sc[tid] = ctx;
    }
    __syncthreads();
    if (tid < 64) {
        float o = bo[tid];
#pragma unroll
        for (int j = 0; j < 64; j++) o += sc[j] * Wo[j * 64 + tid];
        float r = yv[tid] + o;
        float sum = r, sq = r * r;
#pragma unroll
        for (int d = 32; d; d >>= 1) { sum += __shfl_xor(sum, d); sq += __shfl_xor(sq, d); }
        float mu = sum * (1.f / 64.f);
        float var = sq * (1.f / 64.f) - mu * mu;
        float zz = (r - mu) * rsqrtf(var + 1e-5f) * ln1g[tid] + ln1b[tid];
        z1[(long)bn * 64 + tid] = zz;
    }
}

// ---------------- K7-probe: empirically measure MFMA fragment layouts ----------------
__global__ void mfma_probe_kernel(int* __restrict__ tbl) {
    int lane = threadIdx.x;           // 64 threads
    int quad = lane >> 4, L = lane & 15;
    short one = f2bf(1.0f), Ls = f2bf((float)L);
    bf16x8 ones, lv, alab;
#pragma unroll
    for (int j = 0; j < 8; j++) { ones[j] = one; lv[j] = Ls; alab[j] = f2bf((float)(quad * 8 + j)); }
    f32x4 zero = {0.f, 0.f, 0.f, 0.f};
    f32x4 dm = __builtin_amdgcn_mfma_f32_16x16x32_bf16(lv, ones, zero, 0, 0, 0);
    f32x4 dn = __builtin_amdgcn_mfma_f32_16x16x32_bf16(ones, lv, zero, 0, 0, 0);
#pragma unroll
    for (int r = 0; r < 4; r++) {
        tbl[lane * 4 + r]       = (int)(dm[r] * (1.f / 32.f) + 0.5f);
        tbl[256 + lane * 4 + r] = (int)(dn[r] * (1.f / 32.f) + 0.5f);
    }
    for (int b = 0; b < 32; b++) {
        bf16x8 bh;
#pragma unroll
        for (int j = 0; j < 8; j++) bh[j] = (quad == (b >> 3) && j == (b & 7)) ? one : (short)0;
        f32x4 d = __builtin_amdgcn_mfma_f32_16x16x32_bf16(alab, bh, zero, 0, 0, 0);
        int a = (int)(d[0] + 0.5f);
        if (lane == 0) tbl[512 + a] = b;
    }
}

// ---------------- K7-pre: pack W1/W2 to bf16 using measured B-slot pairing ----------------
__global__ void pack_w1_kernel(const float* __restrict__ W1, short* __restrict__ pw1,
                               const int* __restrict__ tbl) {
    int i = blockIdx.x * 256 + threadIdx.x;   // over 64*2048
    if (i >= 64 * 2048) return;
    int k = i >> 11, n = i & 2047;
    int s = k >> 5, kp = k & 31;
    int b = tbl[512 + kp];
    int lane = (b >> 3) * 16 + (n & 15), jj = b & 7;
    int t = n >> 4;
    pw1[(((t * 2 + s) * 64 + lane) << 3) + jj] = f2bf(W1[i]);
}
__global__ void pack_w2_kernel(const float* __restrict__ W2, short* __restrict__ pw2,
                               const int* __restrict__ tbl) {
    int i = blockIdx.x * 256 + threadIdx.x;   // over 2048*64
    if (i >= 2048 * 64) return;
    int k = i >> 6, n = i & 63;
    int kt = k >> 5, kp = k & 31;
    int b = tbl[512 + kp];
    int lane = (b >> 3) * 16 + (n & 15), jj = b & 7;
    int nt = n >> 4;
    pw2[(((kt * 4 + nt) * 64 + lane) << 3) + jj] = f2bf(W2[i]);
}

// ---------------- K7: FF via bf16 MFMA (layout-table-driven) + residual + LN2 -> out ----------------
__global__ __launch_bounds__(256) void ff_mfma_kernel(const float* __restrict__ z1,
        const short* __restrict__ pw1, const short* __restrict__ pw2,
        const float* __restrict__ b1, const float* __restrict__ b2,
        const float* __restrict__ ln2g, const float* __restrict__ ln2b,
        const int* __restrict__ tbl, float* __restrict__ out) {
    __shared__ __align__(16) short zb[16 * 72];
    __shared__ __align__(16) short hb[4][16 * 520];
    __shared__ float part[4 * 16 * 64];
    int tid = threadIdx.x;
    int row0 = blockIdx.x * 16;
    for (int i = tid; i < 1024; i += 256)
        zb[(i >> 6) * 72 + (i & 63)] = f2bf(z1[(long)row0 * 64 + i]);
    __syncthreads();
    int lane = tid & 63, wv = tid >> 6;
    int quad = lane >> 4, m16 = lane & 15;
    int mo[4], no[4];
#pragma unroll
    for (int r = 0; r < 4; r++) { mo[r] = tbl[lane * 4 + r]; no[r] = tbl[256 + lane * 4 + r]; }
    bf16x8 a0 = *(const bf16x8*)&zb[m16 * 72 + quad * 8];
    bf16x8 a1 = *(const bf16x8*)&zb[m16 * 72 + 32 + quad * 8];
    const short* pb1 = pw1 + (size_t)wv * 32 * 2 * 512;
    short* hbw = &hb[wv][0];
#pragma unroll 4
    for (int t = 0; t < 32; t++) {
        bf16x8 bA = *(const bf16x8*)(pb1 + ((t * 2 + 0) << 9) + (lane << 3));
        bf16x8 bB = *(const bf16x8*)(pb1 + ((t * 2 + 1) << 9) + (lane << 3));
        f32x4 acc = {0.f, 0.f, 0.f, 0.f};
        acc = __builtin_amdgcn_mfma_f32_16x16x32_bf16(a0, bA, acc, 0, 0, 0);
        acc = __builtin_amdgcn_mfma_f32_16x16x32_bf16(a1, bB, acc, 0, 0, 0);
#pragma unroll
        for (int r = 0; r < 4; r++) {
            float v = acc[r] + b1[wv * 512 + t * 16 + no[r]];
            v = v > 0.f ? v : 0.f;
            hbw[mo[r] * 520 + t * 16 + no[r]] = f2bf(v);
        }
    }
    __syncthreads();
    f32x4 acc2[4] = {{0.f,0.f,0.f,0.f},{0.f,0.f,0.f,0.f},{0.f,0.f,0.f,0.f},{0.f,0.f,0.f,0.f}};
    const short* pb2 = pw2 + (size_t)wv * 16 * 4 * 512;
#pragma unroll 2
    for (int kt = 0; kt < 16; kt++) {
        bf16x8 af = *(const bf16x8*)&hbw[m16 * 520 + kt * 32 + quad * 8];
#pragma unroll
        for (int nt = 0; nt < 4; nt++) {
            bf16x8 bfr = *(const bf16x8*)(pb2 + ((kt * 4 + nt) << 9) + (lane << 3));
            acc2[nt] = __builtin_amdgcn_mfma_f32_16x16x32_bf16(af, bfr, acc2[nt], 0, 0, 0);
        }
    }
#pragma unroll
    for (int nt = 0; nt < 4; nt++)
#pragma unroll
        for (int r = 0; r < 4; r++)
            part[wv * 1024 + mo[r] * 64 + nt * 16 + no[r]] = acc2[nt][r];
    __syncthreads();
    int col = tid & 63, rq = tid >> 6;
    float g = ln2g[col], bb = ln2b[col], bias2 = b2[col];
#pragma unroll
    for (int k2 = 0; k2 < 4; k2++) {
        int r = rq + k2 * 4;
        float val = part[r * 64 + col] + part[1024 + r * 64 + col]
                  + part[2048 + r * 64 + col] + part[3072 + r * 64 + col]
                  + z1[(long)(row0 + r) * 64 + col] + bias2;
        float sum = val, sq = val * val;
#pragma unroll
        for (int dlt = 32; dlt; dlt >>= 1) { sum += __shfl_xor(sum, dlt); sq += __shfl_xor(sq, dlt); }
        float mu = sum * (1.f / 64.f);
        float var = sq * (1.f / 64.f) - mu * mu;
        out[(long)(row0 + r) * 64 + col] = (val - mu) * rsqrtf(var + 1e-5f) * g + bb;
    }
}

extern "C" void kernel_launch(void* const* d_in, const int* in_sizes, int n_in,
                              void* d_out, int out_size, void* d_ws, size_t ws_size,
                              hipStream_t stream) {
    const float* x_seq      = (const float*)d_in[0];
    const int*   edge_index = (const int*)  d_in[1];
    const float* edge_weight= (const float*)d_in[2];
    const float* W_gat      = (const float*)d_in[3];
    const float* att_src    = (const float*)d_in[4];
    const float* att_dst    = (const float*)d_in[5];
    const float* W_edge     = (const float*)d_in[6];
    const float* att_edge   = (const float*)d_in[7];
    const float* gat_bias   = (const float*)d_in[8];
    const float* W_proj     = (const float*)d_in[9];
    const float* b_proj     = (const float*)d_in[10];
    const float* Wqkv       = (const float*)d_in[11];
    const float* bqkv       = (const float*)d_in[12];
    const float* Wo         = (const float*)d_in[13];
    const float* bo         = (const float*)d_in[14];
    const float* ln1g       = (const float*)d_in[15];
    const float* ln1b       = (const float*)d_in[16];
    const float* W1         = (const float*)d_in[17];
    const float* b1         = (const float*)d_in[18];
    const float* W2         = (const float*)d_in[19];
    const float* b2         = (const float*)d_in[20];
    const float* ln2g       = (const float*)d_in[21];
    const float* ln2b       = (const float*)d_in[22];
    float* outp = (float*)d_out;

    float* wsf = (float*)d_ws;
    float* h      = wsf + OFF_H;
    float* a_src  = wsf + OFF_ASRC;
    float* a_dst  = wsf + OFF_ADST;
    float* outg   = wsf + OFF_Y;
    float* Wfused = wsf + OFF_WF;
    float* bfv    = Wfused + 32 * 192;
    float* z1     = wsf + OFF_Z1;
    float* scal   = wsf + OFF_SCAL;
    int*   rowptr = (int*)(wsf + OFF_INTS);
    int*   cnt    = rowptr + 2001;
    int*   csr_src= cnt + 2000;
    float* csr_ew = wsf + OFF_CSREW;
    short* pw1    = (short*)(wsf + OFF_H);          // h dead after gat_agg
    short* pw2    = pw1 + 64 * 2048;
    int*   tbl    = (int*)(wsf + OFF_TBL);

    hipMemsetAsync(scal, 0, sizeof(float), stream);
    hipMemsetAsync(cnt, 0, NV * sizeof(int), stream);
    ew_sum_kernel<<<(EV + 255) / 256, 256, 0, stream>>>(edge_weight, scal);
    prep2_kernel<<<1, 128, 0, stream>>>(W_edge, att_edge, scal);
    fuse_kernel<<<24, 256, 0, stream>>>(W_proj, b_proj, Wqkv, bqkv, Wfused, bfv);
    hist_kernel<<<(ETV + 255) / 256, 256, 0, stream>>>(edge_index, cnt);
    scan_kernel<<<1, 256, 0, stream>>>(cnt, rowptr, cnt);
    scatter_kernel<<<(ETV + 255) / 256, 256, 0, stream>>>(edge_index, edge_weight, scal, cnt, csr_src, csr_ew);
    gat_h_kernel<<<GV * NV / 16, 256, 0, stream>>>(x_seq, W_gat, att_src, att_dst, h, a_src, a_dst);
    gat_agg_kernel<<<GV * NV / 4, 256, 0, stream>>>(h, a_src, a_dst, rowptr, csr_src, csr_ew, scal,
                                                    gat_bias, outg);
    mfma_probe_kernel<<<1, 64, 0, stream>>>(tbl);
    pack_w1_kernel<<<(64 * 2048 + 255) / 256, 256, 0, stream>>>(W1, pw1, tbl);
    pack_w2_kernel<<<(2048 * 64 + 255) / 256, 256, 0, stream>>>(W2, pw2, tbl);
    attn_kernel<<<BV * NV, 256, 0, stream>>>(outg, Wfused, bfv, W_proj, b_proj, Wo, bo, ln1g, ln1b, z1);
    ff_mfma_kernel<<<BV * NV / 16, 256, 0, stream>>>(z1, pw1, pw2, b1, b2, ln2g, ln2b, tbl, outp);
}

// Round 9
// 233.054 us; speedup vs baseline: 2.1065x; 1.0493x over previous
//
#include <hip/hip_runtime.h>
#include <math.h>

#define BV 2
#define TV 16
#define NV 2000
#define FIN 16
#define EV 32000
#define ETV 34000
#define GV 32
#define DD 64
#define FFV 2048

// workspace layout (float offsets)
#define OFF_H     0L          // h bf16 [32*2000*128 ushorts]
#define OFF_ASRC  8192000L
#define OFF_ADST  8448000L
#define OFF_Y     8704000L    // outg [2*2000*16*32] = 2048000 floats
#define OFF_WF    10752000L   // fused Wf [32*192], bfv [192]
#define OFF_Z1    12800000L
#define OFF_SCAL  13056000L   // scal[16] then cnt[2000] (one memset covers both)
#define OFF_PACK  14000000L   // pw1 [131072 bf16], pw2 [131072 bf16]
#define OFF_TBL   14200000L   // int tbl[544]

typedef __attribute__((ext_vector_type(8))) short bf16x8;
typedef __attribute__((ext_vector_type(4))) float f32x4;

__device__ __forceinline__ short f2bf(float f) {
    union { float f; unsigned u; } v; v.f = f;
    unsigned r = v.u + 0x7FFFu + ((v.u >> 16) & 1u);   // round-to-nearest-even
    return (short)(r >> 16);
}
__device__ __forceinline__ float bflo(unsigned u) { union { unsigned u; float f; } v; v.u = u << 16; return v.f; }
__device__ __forceinline__ float bfhi(unsigned u) { union { unsigned u; float f; } v; v.u = u & 0xffff0000u; return v.f; }

// ---------------- K_A: edge-weight sum (atomic) + in-degree histogram ----------------
__global__ void ew_hist_kernel(const int* __restrict__ edge_index, const float* __restrict__ ew,
                               int* __restrict__ deg, float* __restrict__ scal) {
    int e = blockIdx.x * 256 + threadIdx.x;
    float v = (e < EV) ? ew[e] : 0.f;
#pragma unroll
    for (int d = 32; d; d >>= 1) v += __shfl_xor(v, d);
    if ((threadIdx.x & 63) == 0) atomicAdd(&scal[0], v);
    if (e < ETV) {
        int dst = (e < EV) ? edge_index[EV + e] : (e - EV);
        atomicAdd(&deg[dst], 1);
    }
}

// ---------------- K_B: exclusive scan -> rowptr, copy -> cnt ----------------
__global__ void scan_kernel(const int* __restrict__ deg, int* __restrict__ rowptr, int* __restrict__ cnt) {
    __shared__ int tot[256];
    int tid = threadIdx.x;
    int base = tid * 8;
    int local[8]; int s = 0;
    for (int i = 0; i < 8; i++) { int v = (base + i < NV) ? deg[base + i] : 0; local[i] = s; s += v; }
    tot[tid] = s; __syncthreads();
    for (int d = 1; d < 256; d <<= 1) {
        int v = (tid >= d) ? tot[tid - d] : 0;
        __syncthreads();
        tot[tid] += v;
        __syncthreads();
    }
    int ex = tot[tid] - s;
    for (int i = 0; i < 8; i++) {
        int idx = base + i;
        if (idx < NV) { int rp = ex + local[i]; rowptr[idx] = rp; cnt[idx] = rp; }
    }
    if (tid == 255) rowptr[NV] = tot[255];
}

// ---------------- K_C: fuse (blocks 0-23) + prep2 (block 24) + MFMA probe (block 25) ----------------
__global__ void prep_fuse_probe_kernel(const float* __restrict__ Wproj, const float* __restrict__ bproj,
                                       const float* __restrict__ Wqkv, const float* __restrict__ bqkv,
                                       float* __restrict__ Wf, float* __restrict__ bfv,
                                       const float* __restrict__ W_edge, const float* __restrict__ att_edge,
                                       float* __restrict__ scal, int* __restrict__ tbl) {
    int bid = blockIdx.x, tid = threadIdx.x;
    if (bid < 24) {
        int i = bid * 256 + tid;
        if (i < 32 * 192) {
            int c = i / 192, j = i - c * 192;
            float s = 0.f;
#pragma unroll
            for (int d = 0; d < 64; d++) s += Wproj[c * 64 + d] * Wqkv[d * 192 + j];
            Wf[i] = s;
        }
        if (i < 192) {
            float s = bqkv[i];
#pragma unroll
            for (int d = 0; d < 64; d++) s += bproj[d] * Wqkv[d * 192 + i];
            bfv[i] = s;
        }
    } else if (bid == 24) {
        __shared__ float red[128];
        if (tid < 128) red[tid] = W_edge[tid] * att_edge[tid];
        __syncthreads();
        if (tid == 0) scal[0] = scal[0] * (1.f / (float)EV);
        if (tid < 4) {
            float t = 0.f;
#pragma unroll
            for (int c = 0; c < 32; c++) t += red[tid * 32 + c];
            scal[1 + tid] = t;
        }
    } else {
        if (tid < 64) {
            int lane = tid;
            int quad = lane >> 4, L = lane & 15;
            short one = f2bf(1.0f), Ls = f2bf((float)L);
            bf16x8 ones, lv, alab;
#pragma unroll
            for (int j = 0; j < 8; j++) { ones[j] = one; lv[j] = Ls; alab[j] = f2bf((float)(quad * 8 + j)); }
            f32x4 zero = {0.f, 0.f, 0.f, 0.f};
            f32x4 dm = __builtin_amdgcn_mfma_f32_16x16x32_bf16(lv, ones, zero, 0, 0, 0);
            f32x4 dn = __builtin_amdgcn_mfma_f32_16x16x32_bf16(ones, lv, zero, 0, 0, 0);
#pragma unroll
            for (int r = 0; r < 4; r++) {
                tbl[lane * 4 + r]       = (int)(dm[r] * (1.f / 32.f) + 0.5f);
                tbl[256 + lane * 4 + r] = (int)(dn[r] * (1.f / 32.f) + 0.5f);
            }
            for (int b = 0; b < 32; b++) {
                bf16x8 bh;
#pragma unroll
                for (int j = 0; j < 8; j++) bh[j] = (quad == (b >> 3) && j == (b & 7)) ? one : (short)0;
                f32x4 d = __builtin_amdgcn_mfma_f32_16x16x32_bf16(alab, bh, zero, 0, 0, 0);
                int a = (int)(d[0] + 0.5f);
                if (lane == 0) tbl[512 + a] = b;
            }
        }
    }
}

// ---------------- K_pack: W1 + W2 -> bf16 fragment order (one kernel) ----------------
__global__ void pack_w_kernel(const float* __restrict__ W1, const float* __restrict__ W2,
                              short* __restrict__ pw1, short* __restrict__ pw2,
                              const int* __restrict__ tbl) {
    int idx = blockIdx.x * 256 + threadIdx.x;   // 0..262143
    if (idx < 131072) {
        int i = idx;                             // over 64*2048
        int k = i >> 11, n = i & 2047;
        int s = k >> 5, kp = k & 31;
        int b = tbl[512 + kp];
        int lane = (b >> 3) * 16 + (n & 15), jj = b & 7;
        int t = n >> 4;
        pw1[(((t * 2 + s) * 64 + lane) << 3) + jj] = f2bf(W1[i]);
    } else {
        int i = idx - 131072;                    // over 2048*64
        int k = i >> 6, n = i & 63;
        int kt = k >> 5, kp = k & 31;
        int b = tbl[512 + kp];
        int lane = (b >> 3) * 16 + (n & 15), jj = b & 7;
        int nt = n >> 4;
        pw2[(((kt * 4 + nt) * 64 + lane) << 3) + jj] = f2bf(W2[i]);
    }
}

// ---------------- K_D: scatter edges into CSR ----------------
__global__ void scatter_kernel(const int* __restrict__ edge_index, const float* __restrict__ edge_weight,
                               const float* __restrict__ scal, int* __restrict__ cnt,
                               int* __restrict__ csr_src, float* __restrict__ csr_ew) {
    int e = blockIdx.x * 256 + threadIdx.x;
    if (e >= ETV) return;
    int src, dst; float w;
    if (e < EV) { src = edge_index[e]; dst = edge_index[EV + e]; w = edge_weight[e]; }
    else        { src = dst = e - EV; w = scal[0]; }
    int pos = atomicAdd(&cnt[dst], 1);
    csr_src[pos] = src; csr_ew[pos] = w;
}

// ---------------- K4: h = x@W_gat (bf16 out), a_src, a_dst (4 rows/wave, weights in regs) ----------------
__global__ __launch_bounds__(256) void gat_h_kernel(const float* __restrict__ x, const float* __restrict__ W_gat,
                                                    const float* __restrict__ att_src, const float* __restrict__ att_dst,
                                                    unsigned short* __restrict__ h, float* __restrict__ a_src,
                                                    float* __restrict__ a_dst) {
    int tid = threadIdx.x;
    int lane = tid & 63, wave = tid >> 6;
    int row0 = blockIdx.x * 16 + wave * 4;
    float w0[16], w1[16];
#pragma unroll
    for (int f = 0; f < 16; f++) { w0[f] = W_gat[f * 128 + lane]; w1[f] = W_gat[f * 128 + 64 + lane]; }
    float as0 = att_src[lane], as1 = att_src[lane + 64];
    float ad0 = att_dst[lane], ad1 = att_dst[lane + 64];
#pragma unroll
    for (int r = 0; r < 4; r++) {
        int row = row0 + r;
        const float4* xr = (const float4*)(x + (long)row * 16);
        float4 xa = xr[0], xb = xr[1], xc = xr[2], xd = xr[3];
        float xv[16] = {xa.x, xa.y, xa.z, xa.w, xb.x, xb.y, xb.z, xb.w,
                        xc.x, xc.y, xc.z, xc.w, xd.x, xd.y, xd.z, xd.w};
        float h0 = 0.f, h1 = 0.f;
#pragma unroll
        for (int f = 0; f < 16; f++) { h0 += xv[f] * w0[f]; h1 += xv[f] * w1[f]; }
        h[(long)row * 128 + lane] = (unsigned short)f2bf(h0);
        h[(long)row * 128 + 64 + lane] = (unsigned short)f2bf(h1);
        float p0 = h0 * as0, p1 = h1 * as1;
        float q0 = h0 * ad0, q1 = h1 * ad1;
#pragma unroll
        for (int d = 1; d < 32; d <<= 1) {
            p0 += __shfl_xor(p0, d); p1 += __shfl_xor(p1, d);
            q0 += __shfl_xor(q0, d); q1 += __shfl_xor(q1, d);
        }
        if (lane == 0)  { a_src[row * 4 + 0] = p0; a_src[row * 4 + 2] = p1; a_dst[row * 4 + 0] = q0; a_dst[row * 4 + 2] = q1; }
        if (lane == 32) { a_src[row * 4 + 1] = p0; a_src[row * 4 + 3] = p1; a_dst[row * 4 + 1] = q0; a_dst[row * 4 + 3] = q1; }
    }
}

// ---------------- K5: segment softmax + aggregation (bf16 h, 4 edges/iter) -> outg ----------------
// lane = quarter*16 + cg: quarter = edge slot mod 4, cg = channel group (8 ch each).
__global__ __launch_bounds__(256) void gat_agg_kernel(const unsigned short* __restrict__ h,
                                                      const float* __restrict__ a_src,
                                                      const float* __restrict__ a_dst, const int* __restrict__ rowptr,
                                                      const int* __restrict__ csr_src, const float* __restrict__ csr_ew,
                                                      const float* __restrict__ scal, const float* __restrict__ gat_bias,
                                                      float* __restrict__ outg) {
    __shared__ int   ssrc[4][64];
    __shared__ float swt[4][4][65];
    int tid = threadIdx.x;
    int lane = tid & 63, wave = tid >> 6;
    int bid = blockIdx.x;
    int xcd = bid & 7, j = bid >> 3;
    int g = xcd * 4 + j / 500;
    int n = (j % 500) * 4 + wave;
    int w = g * NV + n;
    float s0 = scal[1], s1 = scal[2], s2 = scal[3], s3 = scal[4];
    const float4 ad = *(const float4*)(a_dst + (long)w * 4);
    const float* asrc_g = a_src + (long)g * NV * 4;
    const unsigned short* hg = h + (long)g * NV * 128;
    int start = rowptr[n], end = rowptr[n + 1];
    int quarter = lane >> 4, cg = lane & 15;
    int hsel = cg >> 2;                 // head of this 8-channel group
    float den0 = 0.f, den1 = 0.f, den2 = 0.f, den3 = 0.f;
    float m0 = 0.f, m1 = 0.f, m2 = 0.f, m3 = 0.f, m4 = 0.f, m5 = 0.f, m6 = 0.f, m7 = 0.f;
    for (int base = start; base < end; base += 64) {
        int idx = base + lane;
        int se = 0; float e0 = 0.f, e1 = 0.f, e2 = 0.f, e3 = 0.f;
        if (idx < end) {
            se = csr_src[idx]; float ew = csr_ew[idx];
            float4 as = *(const float4*)(asrc_g + se * 4);
            float l0 = as.x + ad.x + ew * s0; l0 = l0 > 0.f ? l0 : 0.2f * l0; e0 = __expf(l0);
            float l1 = as.y + ad.y + ew * s1; l1 = l1 > 0.f ? l1 : 0.2f * l1; e1 = __expf(l1);
            float l2 = as.z + ad.z + ew * s2; l2 = l2 > 0.f ? l2 : 0.2f * l2; e2 = __expf(l2);
            float l3 = as.w + ad.w + ew * s3; l3 = l3 > 0.f ? l3 : 0.2f * l3; e3 = __expf(l3);
            den0 += e0; den1 += e1; den2 += e2; den3 += e3;
        }
        ssrc[wave][lane] = se;
        swt[wave][0][lane] = e0; swt[wave][1][lane] = e1;
        swt[wave][2][lane] = e2; swt[wave][3][lane] = e3;
        __builtin_amdgcn_wave_barrier();
        int cn = end - base; if (cn > 64) cn = 64;
        int nq = (cn + 3) >> 2;
#pragma unroll 4
        for (int i = 0; i < nq; i++) {
            int slot = 4 * i + quarter;
            int sse = ssrc[wave][slot];
            float wt = swt[wave][hsel][slot];          // staged 0 for slots >= cn
            const uint4 hv = *(const uint4*)(hg + ((long)sse << 7) + (cg << 3));
            m0 += wt * bflo(hv.x); m1 += wt * bfhi(hv.x);
            m2 += wt * bflo(hv.y); m3 += wt * bfhi(hv.y);
            m4 += wt * bflo(hv.z); m5 += wt * bfhi(hv.z);
            m6 += wt * bflo(hv.w); m7 += wt * bfhi(hv.w);
        }
        __builtin_amdgcn_wave_barrier();
    }
#pragma unroll
    for (int d = 32; d; d >>= 1) {
        den0 += __shfl_xor(den0, d); den1 += __shfl_xor(den1, d);
        den2 += __shfl_xor(den2, d); den3 += __shfl_xor(den3, d);
    }
    float denh = (hsel == 0) ? den0 : (hsel == 1) ? den1 : (hsel == 2) ? den2 : den3;
    float inv = 1.f / (denh + 1e-16f);
    m0 *= inv; m1 *= inv; m2 *= inv; m3 *= inv; m4 *= inv; m5 *= inv; m6 *= inv; m7 *= inv;
    // sum edge quarters (lane bits 4,5), then head mean (lane bits 2,3 = cg bits 2,3)
#pragma unroll
    for (int d = 16; d <= 32; d <<= 1) {
        m0 += __shfl_xor(m0, d); m1 += __shfl_xor(m1, d); m2 += __shfl_xor(m2, d); m3 += __shfl_xor(m3, d);
        m4 += __shfl_xor(m4, d); m5 += __shfl_xor(m5, d); m6 += __shfl_xor(m6, d); m7 += __shfl_xor(m7, d);
    }
#pragma unroll
    for (int d = 4; d <= 8; d <<= 1) {
        m0 += __shfl_xor(m0, d); m1 += __shfl_xor(m1, d); m2 += __shfl_xor(m2, d); m3 += __shfl_xor(m3, d);
        m4 += __shfl_xor(m4, d); m5 += __shfl_xor(m5, d); m6 += __shfl_xor(m6, d); m7 += __shfl_xor(m7, d);
    }
    if (lane < 4) {                       // quarter==0, cg==lane: channels lane*8..lane*8+7
        int cb = lane * 8;
        const float4 gb0 = *(const float4*)(gat_bias + cb);
        const float4 gb1 = *(const float4*)(gat_bias + cb + 4);
        int b = g / TV, tt = g - b * TV;
        float* op = outg + (((long)(b * NV + n)) * TV + tt) * 32 + cb;
        float4 o0 = {0.25f * m0 + gb0.x, 0.25f * m1 + gb0.y, 0.25f * m2 + gb0.z, 0.25f * m3 + gb0.w};
        float4 o1 = {0.25f * m4 + gb1.x, 0.25f * m5 + gb1.y, 0.25f * m6 + gb1.z, 0.25f * m7 + gb1.w};
        *(float4*)op = o0;
        *(float4*)(op + 4) = o1;
    }
}

// ---------------- K6: fused qkv (K=32) + attention + Wo + LN1 -> z1 ----------------
__global__ __launch_bounds__(256) void attn_kernel(const float* __restrict__ og, const float* __restrict__ Wf,
                                                   const float* __restrict__ bfv, const float* __restrict__ Wproj,
                                                   const float* __restrict__ bproj, const float* __restrict__ Wo,
                                                   const float* __restrict__ bo, const float* __restrict__ ln1g,
                                                   const float* __restrict__ ln1b, float* __restrict__ z1) {
    __shared__ float ot[512], wkvf[4096], kb[1024], vb[1024], qv[64], pv[64], sc[64], yv[64];
    int tid = threadIdx.x;
    int bn = blockIdx.x;
    const float* ob = og + (long)bn * 512;
    for (int i = tid; i < 512; i += 256) ot[i] = ob[i];
    for (int i = tid; i < 4096; i += 256) { int d = i >> 7, j = i & 127; wkvf[i] = Wf[d * 192 + 64 + j]; }
    __syncthreads();
    {
        int j = tid & 127, tb = tid >> 7;
        float wcol[32];
#pragma unroll
        for (int d = 0; d < 32; d++) wcol[d] = wkvf[d * 128 + j];
        float bias = bfv[64 + j];
#pragma unroll
        for (int k = 0; k < 8; k++) {
            int t = 2 * k + tb;
            const float* orow = &ot[t * 32];
            float a = bias;
#pragma unroll
            for (int d = 0; d < 32; d++) a += orow[d] * wcol[d];
            if (j < 64) kb[t * 64 + j] = a; else vb[t * 64 + (j - 64)] = a;
        }
    }
    if (tid < 64) {
        float a = bfv[tid];
        float yr = bproj[tid];
#pragma unroll
        for (int d = 0; d < 32; d++) {
            float od = ot[15 * 32 + d];
            a  += od * Wf[d * 192 + tid];
            yr += od * Wproj[d * 64 + tid];
        }
        qv[tid] = a; yv[tid] = yr;
    }
    __syncthreads();
    if (tid < 64) {
        int hh = tid >> 4, t = tid & 15;
        float s = 0.f;
#pragma unroll
        for (int dd = 0; dd < 16; dd++) s += qv[hh * 16 + dd] * kb[t * 64 + hh * 16 + dd];
        sc[tid] = s * 0.25f;
    }
    __syncthreads();
    if (tid < 64) {
        int hh = tid >> 4;
        float m = -INFINITY;
        for (int t = 0; t < 16; t++) m = fmaxf(m, sc[hh * 16 + t]);
        float den = 0.f;
        for (int t = 0; t < 16; t++) den += __expf(sc[hh * 16 + t] - m);
        pv[tid] = __expf(sc[tid] - m) / den;
    }
    __syncthreads();
    if (tid < 64) {
        int hh = tid >> 4;
        float ctx = 0.f;
#pragma unroll
        for (int t = 0; t < 16; t++) ctx += pv[hh * 16 + t] * vb[t * 64 + tid];
        sc[tid] = ctx;
    }
    __syncthreads();
    if (tid < 64) {
        float o = bo[tid];
#pragma unroll
        for (int j = 0; j < 64; j++) o += sc[j] * Wo[j * 64 + tid];
        float r = yv[tid] + o;
        float sum = r, sq = r * r;
#pragma unroll
        for (int d = 32; d; d >>= 1) { sum += __shfl_xor(sum, d); sq += __shfl_xor(sq, d); }
        float mu = sum * (1.f / 64.f);
        float var = sq * (1.f / 64.f) - mu * mu;
        float zz = (r - mu) * rsqrtf(var + 1e-5f) * ln1g[tid] + ln1b[tid];
        z1[(long)bn * 64 + tid] = zz;
    }
}

// ---------------- K7: FF via bf16 MFMA (layout-table-driven) + residual + LN2 -> out ----------------
__global__ __launch_bounds__(256) void ff_mfma_kernel(const float* __restrict__ z1,
        const short* __restrict__ pw1, const short* __restrict__ pw2,
        const float* __restrict__ b1, const float* __restrict__ b2,
        const float* __restrict__ ln2g, const float* __restrict__ ln2b,
        const int* __restrict__ tbl, float* __restrict__ out) {
    __shared__ __align__(16) short zb[16 * 72];
    __shared__ __align__(16) short hb[4][16 * 520];
    __shared__ float part[4 * 16 * 64];
    int tid = threadIdx.x;
    int row0 = blockIdx.x * 16;
    for (int i = tid; i < 1024; i += 256)
        zb[(i >> 6) * 72 + (i & 63)] = f2bf(z1[(long)row0 * 64 + i]);
    __syncthreads();
    int lane = tid & 63, wv = tid >> 6;
    int quad = lane >> 4, m16 = lane & 15;
    int mo[4], no[4];
#pragma unroll
    for (int r = 0; r < 4; r++) { mo[r] = tbl[lane * 4 + r]; no[r] = tbl[256 + lane * 4 + r]; }
    bf16x8 a0 = *(const bf16x8*)&zb[m16 * 72 + quad * 8];
    bf16x8 a1 = *(const bf16x8*)&zb[m16 * 72 + 32 + quad * 8];
    const short* pb1 = pw1 + (size_t)wv * 32 * 2 * 512;
    short* hbw = &hb[wv][0];
#pragma unroll 4
    for (int t = 0; t < 32; t++) {
        bf16x8 bA = *(const bf16x8*)(pb1 + ((t * 2 + 0) << 9) + (lane << 3));
        bf16x8 bB = *(const bf16x8*)(pb1 + ((t * 2 + 1) << 9) + (lane << 3));
        f32x4 acc = {0.f, 0.f, 0.f, 0.f};
        acc = __builtin_amdgcn_mfma_f32_16x16x32_bf16(a0, bA, acc, 0, 0, 0);
        acc = __builtin_amdgcn_mfma_f32_16x16x32_bf16(a1, bB, acc, 0, 0, 0);
#pragma unroll
        for (int r = 0; r < 4; r++) {
            float v = acc[r] + b1[wv * 512 + t * 16 + no[r]];
            v = v > 0.f ? v : 0.f;
            hbw[mo[r] * 520 + t * 16 + no[r]] = f2bf(v);
        }
    }
    __syncthreads();
    f32x4 acc2[4] = {{0.f,0.f,0.f,0.f},{0.f,0.f,0.f,0.f},{0.f,0.f,0.f,0.f},{0.f,0.f,0.f,0.f}};
    const short* pb2 = pw2 + (size_t)wv * 16 * 4 * 512;
#pragma unroll 2
    for (int kt = 0; kt < 16; kt++) {
        bf16x8 af = *(const bf16x8*)&hbw[m16 * 520 + kt * 32 + quad * 8];
#pragma unroll
        for (int nt = 0; nt < 4; nt++) {
            bf16x8 bfr = *(const bf16x8*)(pb2 + ((kt * 4 + nt) << 9) + (lane << 3));
            acc2[nt] = __builtin_amdgcn_mfma_f32_16x16x32_bf16(af, bfr, acc2[nt], 0, 0, 0);
        }
    }
#pragma unroll
    for (int nt = 0; nt < 4; nt++)
#pragma unroll
        for (int r = 0; r < 4; r++)
            part[wv * 1024 + mo[r] * 64 + nt * 16 + no[r]] = acc2[nt][r];
    __syncthreads();
    int col = tid & 63, rq = tid >> 6;
    float g = ln2g[col], bb = ln2b[col], bias2 = b2[col];
#pragma unroll
    for (int k2 = 0; k2 < 4; k2++) {
        int r = rq + k2 * 4;
        float val = part[r * 64 + col] + part[1024 + r * 64 + col]
                  + part[2048 + r * 64 + col] + part[3072 + r * 64 + col]
                  + z1[(long)(row0 + r) * 64 + col] + bias2;
        float sum = val, sq = val * val;
#pragma unroll
        for (int dlt = 32; dlt; dlt >>= 1) { sum += __shfl_xor(sum, dlt); sq += __shfl_xor(sq, dlt); }
        float mu = sum * (1.f / 64.f);
        float var = sq * (1.f / 64.f) - mu * mu;
        out[(long)(row0 + r) * 64 + col] = (val - mu) * rsqrtf(var + 1e-5f) * g + bb;
    }
}

extern "C" void kernel_launch(void* const* d_in, const int* in_sizes, int n_in,
                              void* d_out, int out_size, void* d_ws, size_t ws_size,
                              hipStream_t stream) {
    const float* x_seq      = (const float*)d_in[0];
    const int*   edge_index = (const int*)  d_in[1];
    const float* edge_weight= (const float*)d_in[2];
    const float* W_gat      = (const float*)d_in[3];
    const float* att_src    = (const float*)d_in[4];
    const float* att_dst    = (const float*)d_in[5];
    const float* W_edge     = (const float*)d_in[6];
    const float* att_edge   = (const float*)d_in[7];
    const float* gat_bias   = (const float*)d_in[8];
    const float* W_proj     = (const float*)d_in[9];
    const float* b_proj     = (const float*)d_in[10];
    const float* Wqkv       = (const float*)d_in[11];
    const float* bqkv       = (const float*)d_in[12];
    const float* Wo         = (const float*)d_in[13];
    const float* bo         = (const float*)d_in[14];
    const float* ln1g       = (const float*)d_in[15];
    const float* ln1b       = (const float*)d_in[16];
    const float* W1         = (const float*)d_in[17];
    const float* b1         = (const float*)d_in[18];
    const float* W2         = (const float*)d_in[19];
    const float* b2         = (const float*)d_in[20];
    const float* ln2g       = (const float*)d_in[21];
    const float* ln2b       = (const float*)d_in[22];
    float* outp = (float*)d_out;

    float* wsf = (float*)d_ws;
    unsigned short* h = (unsigned short*)(wsf + OFF_H);
    float* a_src  = wsf + OFF_ASRC;
    float* a_dst  = wsf + OFF_ADST;
    float* outg   = wsf + OFF_Y;
    float* Wfused = wsf + OFF_WF;
    float* bfv    = Wfused + 32 * 192;
    float* z1     = wsf + OFF_Z1;
    float* scal   = wsf + OFF_SCAL;
    int*   cnt    = (int*)(wsf + OFF_SCAL + 16);
    int*   rowptr = cnt + 2000;
    int*   csr_src= rowptr + 2001;
    float* csr_ew = (float*)(csr_src + 34000);
    short* pw1    = (short*)(wsf + OFF_PACK);
    short* pw2    = pw1 + 131072;
    int*   tbl    = (int*)(wsf + OFF_TBL);

    // one memset covers scal[16] + cnt[2000]
    hipMemsetAsync(scal, 0, (16 + NV) * sizeof(float), stream);
    ew_hist_kernel<<<(ETV + 255) / 256, 256, 0, stream>>>(edge_index, edge_weight, cnt, scal);
    scan_kernel<<<1, 256, 0, stream>>>(cnt, rowptr, cnt);
    prep_fuse_probe_kernel<<<26, 256, 0, stream>>>(W_proj, b_proj, Wqkv, bqkv, Wfused, bfv,
                                                   W_edge, att_edge, scal, tbl);
    pack_w_kernel<<<1024, 256, 0, stream>>>(W1, W2, pw1, pw2, tbl);
    scatter_kernel<<<(ETV + 255) / 256, 256, 0, stream>>>(edge_index, edge_weight, scal, cnt, csr_src, csr_ew);
    gat_h_kernel<<<GV * NV / 16, 256, 0, stream>>>(x_seq, W_gat, att_src, att_dst, h, a_src, a_dst);
    gat_agg_kernel<<<GV * NV / 4, 256, 0, stream>>>(h, a_src, a_dst, rowptr, csr_src, csr_ew, scal,
                                                    gat_bias, outg);
    attn_kernel<<<BV * NV, 256, 0, stream>>>(outg, Wfused, bfv, W_proj, b_proj, Wo, bo, ln1g, ln1b, z1);
    ff_mfma_kernel<<<BV * NV / 16, 256, 0, stream>>>(z1, pw1, pw2, b1, b2, ln2g, ln2b, tbl, outp);
}